// Round 2
// baseline (610.867 us; speedup 1.0000x reference)
//
#include <hip/hip_runtime.h>
#include <hip/hip_bf16.h>

// Problem constants (fixed by the reference)
constexpr int NB    = 256;          // graphs
constexpr int KK    = 256;          // destroy sets per graph
constexpr int NPER  = 55;           // nodes per graph
constexpr int NN    = NB * NPER;    // 14080 total nodes
constexpr int EE    = NN * 8;       // 112640 edges
constexpr int EMB   = 64;

// ---------------------------------------------------------------------------
// Fused: node embedding -> h row, zero agg row, scalar MLP on embedding -> t.
// 220 blocks x 64 threads, one node per thread (220 CUs busy, 1 wave each).
__global__ __launch_bounds__(64) void embed_t_kernel(
    const float* __restrict__ coords, const float* __restrict__ We,
    const float* __restrict__ be, float* __restrict__ h,
    float* __restrict__ agg, float* __restrict__ t,
    const float* __restrict__ W1, const float* __restrict__ b1,
    const float* __restrict__ W2, const float* __restrict__ b2,
    const float* __restrict__ W3, const float* __restrict__ b3) {
  __shared__ float sWe[2 * EMB];
  __shared__ float sbe[EMB];
  __shared__ float sW1[64 * 32];
  __shared__ float sW2[32 * 32];
  __shared__ float sW3[32], sb1[32], sb2[32];
  __shared__ float sb3;
  int tid = threadIdx.x;
  for (int i = tid; i < 2 * EMB; i += 64) sWe[i] = We[i];
  for (int i = tid; i < EMB; i += 64) sbe[i] = be[i];
  for (int i = tid; i < 64 * 32; i += 64) sW1[i] = W1[i];
  for (int i = tid; i < 32 * 32; i += 64) sW2[i] = W2[i];
  if (tid < 32) { sW3[tid] = W3[tid]; sb1[tid] = b1[tid]; sb2[tid] = b2[tid]; }
  if (tid == 0) sb3 = b3[0];
  __syncthreads();

  int n = blockIdx.x * 64 + tid;              // n < 14080 (220*64 exactly)
  float cx = coords[n * 2], cy = coords[n * 2 + 1];

  float x[64];
#pragma unroll
  for (int i = 0; i < 64; i++)
    x[i] = fmaf(cx, sWe[i], fmaf(cy, sWe[EMB + i], sbe[i]));

  // write h row + zero agg row (16B vector stores)
  float4* hv = reinterpret_cast<float4*>(h + (size_t)n * 64);
  float4* av = reinterpret_cast<float4*>(agg + (size_t)n * 64);
  float4 z = make_float4(0.f, 0.f, 0.f, 0.f);
#pragma unroll
  for (int i = 0; i < 16; i++) {
    hv[i] = make_float4(x[4 * i], x[4 * i + 1], x[4 * i + 2], x[4 * i + 3]);
    av[i] = z;
  }

  // MLP 64 ->(lrelu) 32 ->(lrelu) 32 -> 1
  float a[32];
#pragma unroll
  for (int j = 0; j < 32; j++) a[j] = sb1[j];
#pragma unroll
  for (int i = 0; i < 64; i++) {
    float xi = x[i];
#pragma unroll
    for (int j = 0; j < 32; j++) a[j] = fmaf(xi, sW1[i * 32 + j], a[j]);
  }
#pragma unroll
  for (int j = 0; j < 32; j++) a[j] = (a[j] >= 0.f) ? a[j] : 0.01f * a[j];

  float c[32];
#pragma unroll
  for (int j = 0; j < 32; j++) c[j] = sb2[j];
#pragma unroll
  for (int i = 0; i < 32; i++) {
    float ai = a[i];
#pragma unroll
    for (int j = 0; j < 32; j++) c[j] = fmaf(ai, sW2[i * 32 + j], c[j]);
  }
#pragma unroll
  for (int j = 0; j < 32; j++) c[j] = (c[j] >= 0.f) ? c[j] : 0.01f * c[j];

  float r = sb3;
#pragma unroll
  for (int i = 0; i < 32; i++) r = fmaf(c[i], sW3[i], r);
  t[n] = r;
}

// ---------------------------------------------------------------------------
// agg[dst[e], :] += h[src[e], :]   (16 threads per edge, float4 loads)
__global__ __launch_bounds__(256) void scatter_kernel(
    const float* __restrict__ h, float* __restrict__ agg,
    const int* __restrict__ src, const int* __restrict__ dst) {
  int gid = blockIdx.x * 256 + threadIdx.x;     // over EE*16
  int e = gid >> 4, q = gid & 15;
  int s = src[e], d = dst[e];
  float4 v = *reinterpret_cast<const float4*>(h + (size_t)s * 64 + q * 4);
  float* ap = agg + (size_t)d * 64 + q * 4;
  atomicAdd(ap + 0, v.x);
  atomicAdd(ap + 1, v.y);
  atomicAdd(ap + 2, v.z);
  atomicAdd(ap + 3, v.w);
}

// ---------------------------------------------------------------------------
// h[n] = relu(h[n]@Ws + agg[n]@Wn + b) + h[n], 32 nodes per 256-thread block.
// Re-zeroes its agg rows after consuming them (block owns rows exclusively).
__global__ __launch_bounds__(256) void gnn_dense_kernel(
    float* __restrict__ h, float* __restrict__ agg,
    const float* __restrict__ Ws, const float* __restrict__ Wn,
    const float* __restrict__ b) {
  __shared__ float sWs[64 * 64];
  __shared__ float sWn[64 * 64];
  __shared__ float sh[32][64];
  __shared__ float sa[32][64];
  int tid = threadIdx.x;
  for (int i = tid; i < 4096; i += 256) { sWs[i] = Ws[i]; sWn[i] = Wn[i]; }
  int base = blockIdx.x * 32;
  float4 z = make_float4(0.f, 0.f, 0.f, 0.f);
  for (int i = tid; i < 32 * 16; i += 256) {          // float4 granularity
    int r = i >> 4, q = i & 15;
    reinterpret_cast<float4*>(&sh[r][0])[q] =
        reinterpret_cast<const float4*>(h + (size_t)(base + r) * 64)[q];
    reinterpret_cast<float4*>(&sa[r][0])[q] =
        reinterpret_cast<const float4*>(agg + (size_t)(base + r) * 64)[q];
    // re-zero agg for the next layer's scatter
    reinterpret_cast<float4*>(agg + (size_t)(base + r) * 64)[q] = z;
  }
  __syncthreads();

  int j = tid & 63;   // output dim
  int g = tid >> 6;   // 4 groups x 8 rows
  float bj = b[j];
#pragma unroll
  for (int nn = 0; nn < 8; nn++) {
    int r = g * 8 + nn;
    float acc = bj;
#pragma unroll
    for (int i = 0; i < 64; i++) {
      acc = fmaf(sh[r][i], sWs[i * 64 + j], acc);
      acc = fmaf(sa[r][i], sWn[i * 64 + j], acc);
    }
    float res = ((acc > 0.f) ? acc : 0.f) + sh[r][j];
    h[(size_t)(base + r) * 64 + j] = res;   // in-place: block owns these rows
  }
}

// ---------------------------------------------------------------------------
// One block per graph b:
//   phase 1: lanes 0..54 of wave 0 run the MLP on final h rows -> s*Wp in LDS
//   phase 2: wave-0 reduce -> gsum
//   phase 3: all 256 threads: out[b,k] = gsum + sum_j t[id_j]*Wp[55+j] + bp
__global__ __launch_bounds__(256) void out_kernel(
    const float* __restrict__ h, const float* __restrict__ t,
    const int* __restrict__ ids, const float* __restrict__ Wp,
    const float* __restrict__ bp, float* __restrict__ out,
    const float* __restrict__ W1, const float* __restrict__ b1,
    const float* __restrict__ W2, const float* __restrict__ b2,
    const float* __restrict__ W3, const float* __restrict__ b3) {
  __shared__ float sW1[64 * 32];
  __shared__ float sW2[32 * 32];
  __shared__ float sW3[32], sb1[32], sb2[32];
  __shared__ float sWp[NPER + 3];
  __shared__ float t_l[NPER];
  __shared__ float sb3, sbp, sgsum;
  int tid = threadIdx.x;
  int b = blockIdx.x;
  for (int i = tid; i < 64 * 32; i += 256) sW1[i] = W1[i];
  for (int i = tid; i < 32 * 32; i += 256) sW2[i] = W2[i];
  if (tid < 32) { sW3[tid] = W3[tid]; sb1[tid] = b1[tid]; sb2[tid] = b2[tid]; }
  if (tid < NPER + 3) sWp[tid] = Wp[tid];
  if (tid < NPER) t_l[tid] = t[b * NPER + tid];
  if (tid == 0) { sb3 = b3[0]; sbp = bp[0]; }
  __syncthreads();

  if (tid < 64) {     // wave 0 only
    float v = 0.f;
    if (tid < NPER) {
      float x[64];
      const float4* Xv = reinterpret_cast<const float4*>(h + (size_t)(b * NPER + tid) * 64);
#pragma unroll
      for (int i = 0; i < 16; i++) {
        float4 w = Xv[i];
        x[4 * i] = w.x; x[4 * i + 1] = w.y; x[4 * i + 2] = w.z; x[4 * i + 3] = w.w;
      }
      float a[32];
#pragma unroll
      for (int j = 0; j < 32; j++) a[j] = sb1[j];
#pragma unroll
      for (int i = 0; i < 64; i++) {
        float xi = x[i];
#pragma unroll
        for (int j = 0; j < 32; j++) a[j] = fmaf(xi, sW1[i * 32 + j], a[j]);
      }
#pragma unroll
      for (int j = 0; j < 32; j++) a[j] = (a[j] >= 0.f) ? a[j] : 0.01f * a[j];
      float c[32];
#pragma unroll
      for (int j = 0; j < 32; j++) c[j] = sb2[j];
#pragma unroll
      for (int i = 0; i < 32; i++) {
        float ai = a[i];
#pragma unroll
        for (int j = 0; j < 32; j++) c[j] = fmaf(ai, sW2[i * 32 + j], c[j]);
      }
#pragma unroll
      for (int j = 0; j < 32; j++) c[j] = (c[j] >= 0.f) ? c[j] : 0.01f * c[j];
      float r = sb3;
#pragma unroll
      for (int i = 0; i < 32; i++) r = fmaf(c[i], sW3[i], r);
      v = r * sWp[tid];
    }
#pragma unroll
    for (int off = 32; off > 0; off >>= 1) v += __shfl_down(v, off, 64);
    if (tid == 0) sgsum = v;
  }
  __syncthreads();

  // phase 3: one (b,k) per thread
  const int* id = ids + ((size_t)b * KK + tid) * 3;
  int i0 = id[0], i1 = id[1], i2 = id[2];
  float acc = sgsum + sbp;
  acc = fmaf(t_l[i0], sWp[NPER + 0], acc);
  acc = fmaf(t_l[i1], sWp[NPER + 1], acc);
  acc = fmaf(t_l[i2], sWp[NPER + 2], acc);
  out[(size_t)b * KK + tid] = acc;
}

// ---------------------------------------------------------------------------
extern "C" void kernel_launch(void* const* d_in, const int* in_sizes, int n_in,
                              void* d_out, int out_size, void* d_ws, size_t ws_size,
                              hipStream_t stream) {
  const float* coords = (const float*)d_in[0];
  const int*   src    = (const int*)d_in[1];
  const int*   dst    = (const int*)d_in[2];
  const int*   ids    = (const int*)d_in[3];
  const float* We     = (const float*)d_in[4];
  const float* be     = (const float*)d_in[5];
  const float* Wself  = (const float*)d_in[6];
  const float* Wneigh = (const float*)d_in[7];
  const float* gb     = (const float*)d_in[8];
  const float* W1     = (const float*)d_in[9];
  const float* b1     = (const float*)d_in[10];
  const float* W2     = (const float*)d_in[11];
  const float* b2     = (const float*)d_in[12];
  const float* W3     = (const float*)d_in[13];
  const float* b3     = (const float*)d_in[14];
  const float* Wp     = (const float*)d_in[15];
  const float* bp     = (const float*)d_in[16];
  float* out = (float*)d_out;

  float* ws  = (float*)d_ws;
  float* h   = ws;               // NN*64
  float* agg = h + NN * EMB;     // NN*64
  float* t   = agg + NN * EMB;   // NN

  // 1. embedding + destroy-table MLP + agg zero-init   (220 blocks x 64)
  embed_t_kernel<<<NN / 64, 64, 0, stream>>>(coords, We, be, h, agg, t,
                                             W1, b1, W2, b2, W3, b3);
  // 2. three residual GNN layers (in-place on h; dense re-zeroes agg)
  for (int l = 0; l < 3; l++) {
    scatter_kernel<<<EE * 16 / 256, 256, 0, stream>>>(h, agg, src, dst);
    gnn_dense_kernel<<<NN / 32, 256, 0, stream>>>(
        h, agg, Wself + l * EMB * EMB, Wneigh + l * EMB * EMB, gb + l * EMB);
  }
  // 3. fused final MLP + graph reduce + output gather  (one block per graph)
  out_kernel<<<NB, 256, 0, stream>>>(h, t, ids, Wp, bp, out,
                                     W1, b1, W2, b2, W3, b3);
}

// Round 8
// 332.638 us; speedup vs baseline: 1.8364x; 1.8364x over previous
//
#include <hip/hip_runtime.h>
#include <hip/hip_bf16.h>

// Problem constants (fixed by the reference)
constexpr int NB    = 256;          // graphs
constexpr int KK    = 256;          // destroy sets per graph
constexpr int NPER  = 55;           // nodes per graph
constexpr int NN    = NB * NPER;    // 14080 total nodes
constexpr int EE    = NN * 8;       // 112640 edges
constexpr int EMB   = 64;
constexpr int CAP   = 32;           // max in-degree capacity (Poisson(8) tail: safe)

// ---------------------------------------------------------------------------
// Fused: node embedding -> h row, zero deg[n], scalar MLP on embedding -> t.
// 220 blocks x 64 threads, one node per thread.
__global__ __launch_bounds__(64) void embed_t_kernel(
    const float* __restrict__ coords, const float* __restrict__ We,
    const float* __restrict__ be, float* __restrict__ h,
    int* __restrict__ deg, float* __restrict__ t,
    const float* __restrict__ W1, const float* __restrict__ b1,
    const float* __restrict__ W2, const float* __restrict__ b2,
    const float* __restrict__ W3, const float* __restrict__ b3) {
  __shared__ float sWe[2 * EMB];
  __shared__ float sbe[EMB];
  __shared__ float sW1[64 * 32];
  __shared__ float sW2[32 * 32];
  __shared__ float sW3[32], sb1[32], sb2[32];
  __shared__ float sb3;
  int tid = threadIdx.x;
  {
    const float4* W1v = reinterpret_cast<const float4*>(W1);
    const float4* W2v = reinterpret_cast<const float4*>(W2);
    float4* sW1v = reinterpret_cast<float4*>(sW1);
    float4* sW2v = reinterpret_cast<float4*>(sW2);
    for (int i = tid; i < 512; i += 64) sW1v[i] = W1v[i];
    for (int i = tid; i < 256; i += 64) sW2v[i] = W2v[i];
  }
  for (int i = tid; i < 2 * EMB; i += 64) sWe[i] = We[i];
  if (tid < 32) { sW3[tid] = W3[tid]; sb1[tid] = b1[tid]; sb2[tid] = b2[tid]; }
  sbe[tid] = be[tid];
  if (tid == 0) sb3 = b3[0];
  __syncthreads();

  int n = blockIdx.x * 64 + tid;              // n < 14080 (220*64 exactly)
  deg[n] = 0;                                 // init for bucket fill
  float cx = coords[n * 2], cy = coords[n * 2 + 1];

  float x[64];
#pragma unroll
  for (int i = 0; i < 64; i++)
    x[i] = fmaf(cx, sWe[i], fmaf(cy, sWe[EMB + i], sbe[i]));

  float4* hv = reinterpret_cast<float4*>(h + (size_t)n * 64);
#pragma unroll
  for (int i = 0; i < 16; i++)
    hv[i] = make_float4(x[4 * i], x[4 * i + 1], x[4 * i + 2], x[4 * i + 3]);

  // MLP 64 ->(lrelu) 32 ->(lrelu) 32 -> 1 on the pre-GNN embedding
  float a[32];
#pragma unroll
  for (int j = 0; j < 32; j++) a[j] = sb1[j];
#pragma unroll
  for (int i = 0; i < 64; i++) {
    float xi = x[i];
#pragma unroll
    for (int j = 0; j < 32; j++) a[j] = fmaf(xi, sW1[i * 32 + j], a[j]);
  }
#pragma unroll
  for (int j = 0; j < 32; j++) a[j] = (a[j] >= 0.f) ? a[j] : 0.01f * a[j];

  float c[32];
#pragma unroll
  for (int j = 0; j < 32; j++) c[j] = sb2[j];
#pragma unroll
  for (int i = 0; i < 32; i++) {
    float ai = a[i];
#pragma unroll
    for (int j = 0; j < 32; j++) c[j] = fmaf(ai, sW2[i * 32 + j], c[j]);
  }
#pragma unroll
  for (int j = 0; j < 32; j++) c[j] = (c[j] >= 0.f) ? c[j] : 0.01f * c[j];

  float r = sb3;
#pragma unroll
  for (int i = 0; i < 32; i++) r = fmaf(c[i], sW3[i], r);
  t[n] = r;
}

// ---------------------------------------------------------------------------
// Adjacency bucket fill: bucket[d][pos] = src[e] for each edge e with dst[e]=d.
// E int atomics (vs 7.2M float atomics of the old scatter).
__global__ __launch_bounds__(256) void fill_kernel(
    const int* __restrict__ src, const int* __restrict__ dst,
    int* __restrict__ deg, int* __restrict__ bucket) {
  int e = blockIdx.x * 256 + threadIdx.x;     // EE = 440*256 exactly
  int d = dst[e];
  int s = src[e];
  int pos = atomicAdd(&deg[d], 1);
  if (pos < CAP) bucket[d * CAP + pos] = s;
}

// ---------------------------------------------------------------------------
// Fused gather + dense layer:
//   agg[n] = sum_{s in bucket[n]} h_in[s]     (registers -> LDS, no HBM agg)
//   h_out[n] = relu(h_in[n]@Ws + agg@Wn + b) + h_in[n]
// 32 nodes per 256-thread block; double-buffered h (no in-place race).
__global__ __launch_bounds__(256) void gnn_layer_kernel(
    const float* __restrict__ h_in, float* __restrict__ h_out,
    const int* __restrict__ deg, const int* __restrict__ bucket,
    const float* __restrict__ Ws, const float* __restrict__ Wn,
    const float* __restrict__ b) {
  __shared__ float sWs[64 * 64];
  __shared__ float sWn[64 * 64];
  __shared__ float sh[32][64];
  __shared__ float sa[32][64];
  int tid = threadIdx.x;
  int base = blockIdx.x * 32;

  // gather first: dependent loads (deg -> bucket -> h rows) issue early
  {
    int r  = tid >> 3;          // node 0..31
    int c8 = (tid & 7) * 8;     // dim chunk
    int n  = base + r;
    int dg = deg[n];
    if (dg > CAP) dg = CAP;
    const int* bk = bucket + (size_t)n * CAP;
    float acc0 = 0.f, acc1 = 0.f, acc2 = 0.f, acc3 = 0.f;
    float acc4 = 0.f, acc5 = 0.f, acc6 = 0.f, acc7 = 0.f;
    for (int e = 0; e < dg; e++) {
      int s = bk[e];
      const float4* hv = reinterpret_cast<const float4*>(h_in + (size_t)s * 64 + c8);
      float4 v0 = hv[0], v1 = hv[1];
      acc0 += v0.x; acc1 += v0.y; acc2 += v0.z; acc3 += v0.w;
      acc4 += v1.x; acc5 += v1.y; acc6 += v1.z; acc7 += v1.w;
    }
    sa[r][c8 + 0] = acc0; sa[r][c8 + 1] = acc1; sa[r][c8 + 2] = acc2; sa[r][c8 + 3] = acc3;
    sa[r][c8 + 4] = acc4; sa[r][c8 + 5] = acc5; sa[r][c8 + 6] = acc6; sa[r][c8 + 7] = acc7;
  }

  {
    const float4* Wsv = reinterpret_cast<const float4*>(Ws);
    const float4* Wnv = reinterpret_cast<const float4*>(Wn);
    float4* sWsv = reinterpret_cast<float4*>(sWs);
    float4* sWnv = reinterpret_cast<float4*>(sWn);
    for (int i = tid; i < 1024; i += 256) { sWsv[i] = Wsv[i]; sWnv[i] = Wnv[i]; }
  }
  for (int i = tid; i < 32 * 16; i += 256) {          // h rows, float4
    int r = i >> 4, q = i & 15;
    reinterpret_cast<float4*>(&sh[r][0])[q] =
        reinterpret_cast<const float4*>(h_in + (size_t)(base + r) * 64)[q];
  }
  __syncthreads();

  int j = tid & 63;   // output dim
  int g = tid >> 6;   // 4 groups x 8 rows
  float bj = b[j];
#pragma unroll
  for (int nn = 0; nn < 8; nn++) {
    int r = g * 8 + nn;
    float acc = bj;
#pragma unroll
    for (int i = 0; i < 64; i++) {
      acc = fmaf(sh[r][i], sWs[i * 64 + j], acc);
      acc = fmaf(sa[r][i], sWn[i * 64 + j], acc);
    }
    float res = ((acc > 0.f) ? acc : 0.f) + sh[r][j];
    h_out[(size_t)(base + r) * 64 + j] = res;
  }
}

// ---------------------------------------------------------------------------
// One block per graph b:
//   phase 1: lanes 0..54 of wave 0 run the MLP on final h rows -> *Wp -> reduce
//   phase 2: all 256 threads: out[b,k] = gsum + sum_j t[id_j]*Wp[55+j] + bp
__global__ __launch_bounds__(256) void out_kernel(
    const float* __restrict__ h, const float* __restrict__ t,
    const int* __restrict__ ids, const float* __restrict__ Wp,
    const float* __restrict__ bp, float* __restrict__ out,
    const float* __restrict__ W1, const float* __restrict__ b1,
    const float* __restrict__ W2, const float* __restrict__ b2,
    const float* __restrict__ W3, const float* __restrict__ b3) {
  __shared__ float sW1[64 * 32];
  __shared__ float sW2[32 * 32];
  __shared__ float sW3[32], sb1[32], sb2[32];
  __shared__ float sWp[NPER + 3];
  __shared__ float t_l[NPER];
  __shared__ float sb3, sbp, sgsum;
  int tid = threadIdx.x;
  int b = blockIdx.x;
  {
    const float4* W1v = reinterpret_cast<const float4*>(W1);
    const float4* W2v = reinterpret_cast<const float4*>(W2);
    float4* sW1v = reinterpret_cast<float4*>(sW1);
    float4* sW2v = reinterpret_cast<float4*>(sW2);
    for (int i = tid; i < 512; i += 256) sW1v[i] = W1v[i];
    for (int i = tid; i < 256; i += 256) sW2v[i] = W2v[i];
  }
  if (tid < 32) { sW3[tid] = W3[tid]; sb1[tid] = b1[tid]; sb2[tid] = b2[tid]; }
  if (tid < NPER + 3) sWp[tid] = Wp[tid];
  if (tid < NPER) t_l[tid] = t[b * NPER + tid];
  if (tid == 0) { sb3 = b3[0]; sbp = bp[0]; }
  __syncthreads();

  if (tid < 64) {     // wave 0 only
    float v = 0.f;
    if (tid < NPER) {
      float x[64];
      const float4* Xv = reinterpret_cast<const float4*>(h + (size_t)(b * NPER + tid) * 64);
#pragma unroll
      for (int i = 0; i < 16; i++) {
        float4 w = Xv[i];
        x[4 * i] = w.x; x[4 * i + 1] = w.y; x[4 * i + 2] = w.z; x[4 * i + 3] = w.w;
      }
      float a[32];
#pragma unroll
      for (int j = 0; j < 32; j++) a[j] = sb1[j];
#pragma unroll
      for (int i = 0; i < 64; i++) {
        float xi = x[i];
#pragma unroll
        for (int j = 0; j < 32; j++) a[j] = fmaf(xi, sW1[i * 32 + j], a[j]);
      }
#pragma unroll
      for (int j = 0; j < 32; j++) a[j] = (a[j] >= 0.f) ? a[j] : 0.01f * a[j];
      float c[32];
#pragma unroll
      for (int j = 0; j < 32; j++) c[j] = sb2[j];
#pragma unroll
      for (int i = 0; i < 32; i++) {
        float ai = a[i];
#pragma unroll
        for (int j = 0; j < 32; j++) c[j] = fmaf(ai, sW2[i * 32 + j], c[j]);
      }
#pragma unroll
      for (int j = 0; j < 32; j++) c[j] = (c[j] >= 0.f) ? c[j] : 0.01f * c[j];
      float r = sb3;
#pragma unroll
      for (int i = 0; i < 32; i++) r = fmaf(c[i], sW3[i], r);
      v = r * sWp[tid];
    }
#pragma unroll
    for (int off = 32; off > 0; off >>= 1) v += __shfl_down(v, off, 64);
    if (tid == 0) sgsum = v;
  }
  __syncthreads();

  // one (b,k) per thread
  const int* id = ids + ((size_t)b * KK + tid) * 3;
  int i0 = id[0], i1 = id[1], i2 = id[2];
  float acc = sgsum + sbp;
  acc = fmaf(t_l[i0], sWp[NPER + 0], acc);
  acc = fmaf(t_l[i1], sWp[NPER + 1], acc);
  acc = fmaf(t_l[i2], sWp[NPER + 2], acc);
  out[(size_t)b * KK + tid] = acc;
}

// ---------------------------------------------------------------------------
extern "C" void kernel_launch(void* const* d_in, const int* in_sizes, int n_in,
                              void* d_out, int out_size, void* d_ws, size_t ws_size,
                              hipStream_t stream) {
  const float* coords = (const float*)d_in[0];
  const int*   src    = (const int*)d_in[1];
  const int*   dst    = (const int*)d_in[2];
  const int*   ids    = (const int*)d_in[3];
  const float* We     = (const float*)d_in[4];
  const float* be     = (const float*)d_in[5];
  const float* Wself  = (const float*)d_in[6];
  const float* Wneigh = (const float*)d_in[7];
  const float* gb     = (const float*)d_in[8];
  const float* W1     = (const float*)d_in[9];
  const float* b1     = (const float*)d_in[10];
  const float* W2     = (const float*)d_in[11];
  const float* b2     = (const float*)d_in[12];
  const float* W3     = (const float*)d_in[13];
  const float* b3     = (const float*)d_in[14];
  const float* Wp     = (const float*)d_in[15];
  const float* bp     = (const float*)d_in[16];
  float* out = (float*)d_out;

  float* ws  = (float*)d_ws;
  float* h0  = ws;                         // NN*64 floats
  float* h1  = h0 + (size_t)NN * EMB;      // NN*64 floats
  float* t   = h1 + (size_t)NN * EMB;      // NN floats
  int* deg    = (int*)(t + NN);            // NN ints
  int* bucket = deg + NN;                  // NN*CAP ints

  // 1. embedding + destroy-table MLP + deg zero-init   (220 blocks x 64)
  embed_t_kernel<<<NN / 64, 64, 0, stream>>>(coords, We, be, h0, deg, t,
                                             W1, b1, W2, b2, W3, b3);
  // 2. adjacency bucket fill (one int atomic per edge)
  fill_kernel<<<EE / 256, 256, 0, stream>>>(src, dst, deg, bucket);
  // 3. three residual GNN layers, double-buffered: h0->h1->h0->h1
  const float* hin = h0;
  float* hout = h1;
  for (int l = 0; l < 3; l++) {
    gnn_layer_kernel<<<NN / 32, 256, 0, stream>>>(
        hin, hout, deg, bucket,
        Wself + l * EMB * EMB, Wneigh + l * EMB * EMB, gb + l * EMB);
    const float* tmp = hout; hout = (float*)hin; hin = tmp;
  }
  // 4. fused final MLP + graph reduce + output gather  (one block per graph)
  //    final h lives in h1 (after odd number of swaps, hin == h1)
  out_kernel<<<NB, 256, 0, stream>>>(hin, t, ids, Wp, bp, out,
                                     W1, b1, W2, b2, W3, b3);
}

// Round 9
// 328.621 us; speedup vs baseline: 1.8589x; 1.0122x over previous
//
#include <hip/hip_runtime.h>
#include <hip/hip_bf16.h>

// Problem constants (fixed by the reference)
constexpr int NB    = 256;          // graphs
constexpr int KK    = 256;          // destroy sets per graph
constexpr int NPER  = 55;           // nodes per graph
constexpr int NN    = NB * NPER;    // 14080 total nodes
constexpr int EE    = NN * 8;       // 112640 edges
constexpr int EMB   = 64;
constexpr int CAP   = 32;           // max in-degree capacity (verified: absmax matches atomic ref)

// ---------------------------------------------------------------------------
// Fused: node embedding -> h row, zero deg[n], scalar MLP on embedding -> t.
// 220 blocks x 64 threads, one node per thread.
__global__ __launch_bounds__(64) void embed_t_kernel(
    const float* __restrict__ coords, const float* __restrict__ We,
    const float* __restrict__ be, float* __restrict__ h,
    int* __restrict__ deg, float* __restrict__ t,
    const float* __restrict__ W1, const float* __restrict__ b1,
    const float* __restrict__ W2, const float* __restrict__ b2,
    const float* __restrict__ W3, const float* __restrict__ b3) {
  __shared__ float sWe[2 * EMB];
  __shared__ float sbe[EMB];
  __shared__ float sW1[64 * 32];
  __shared__ float sW2[32 * 32];
  __shared__ float sW3[32], sb1[32], sb2[32];
  __shared__ float sb3;
  int tid = threadIdx.x;
  {
    const float4* W1v = reinterpret_cast<const float4*>(W1);
    const float4* W2v = reinterpret_cast<const float4*>(W2);
    float4* sW1v = reinterpret_cast<float4*>(sW1);
    float4* sW2v = reinterpret_cast<float4*>(sW2);
    for (int i = tid; i < 512; i += 64) sW1v[i] = W1v[i];
    for (int i = tid; i < 256; i += 64) sW2v[i] = W2v[i];
  }
  for (int i = tid; i < 2 * EMB; i += 64) sWe[i] = We[i];
  if (tid < 32) { sW3[tid] = W3[tid]; sb1[tid] = b1[tid]; sb2[tid] = b2[tid]; }
  sbe[tid] = be[tid];
  if (tid == 0) sb3 = b3[0];
  __syncthreads();

  int n = blockIdx.x * 64 + tid;              // n < 14080 (220*64 exactly)
  deg[n] = 0;                                 // init for bucket fill
  float cx = coords[n * 2], cy = coords[n * 2 + 1];

  float x[64];
#pragma unroll
  for (int i = 0; i < 64; i++)
    x[i] = fmaf(cx, sWe[i], fmaf(cy, sWe[EMB + i], sbe[i]));

  float4* hv = reinterpret_cast<float4*>(h + (size_t)n * 64);
#pragma unroll
  for (int i = 0; i < 16; i++)
    hv[i] = make_float4(x[4 * i], x[4 * i + 1], x[4 * i + 2], x[4 * i + 3]);

  // MLP 64 ->(lrelu) 32 ->(lrelu) 32 -> 1 on the pre-GNN embedding
  float a[32];
#pragma unroll
  for (int j = 0; j < 32; j++) a[j] = sb1[j];
#pragma unroll
  for (int i = 0; i < 64; i++) {
    float xi = x[i];
#pragma unroll
    for (int j = 0; j < 32; j++) a[j] = fmaf(xi, sW1[i * 32 + j], a[j]);
  }
#pragma unroll
  for (int j = 0; j < 32; j++) a[j] = (a[j] >= 0.f) ? a[j] : 0.01f * a[j];

  float c[32];
#pragma unroll
  for (int j = 0; j < 32; j++) c[j] = sb2[j];
#pragma unroll
  for (int i = 0; i < 32; i++) {
    float ai = a[i];
#pragma unroll
    for (int j = 0; j < 32; j++) c[j] = fmaf(ai, sW2[i * 32 + j], c[j]);
  }
#pragma unroll
  for (int j = 0; j < 32; j++) c[j] = (c[j] >= 0.f) ? c[j] : 0.01f * c[j];

  float r = sb3;
#pragma unroll
  for (int i = 0; i < 32; i++) r = fmaf(c[i], sW3[i], r);
  t[n] = r;
}

// ---------------------------------------------------------------------------
// Adjacency bucket fill: bucket[d][pos] = src[e] for each edge e with dst[e]=d.
__global__ __launch_bounds__(256) void fill_kernel(
    const int* __restrict__ src, const int* __restrict__ dst,
    int* __restrict__ deg, int* __restrict__ bucket) {
  int e = blockIdx.x * 256 + threadIdx.x;     // EE = 440*256 exactly
  int d = dst[e];
  int s = src[e];
  int pos = atomicAdd(&deg[d], 1);
  if (pos < CAP) bucket[d * CAP + pos] = s;
}

// ---------------------------------------------------------------------------
// Fused gather + dense layer, latency-optimized:
//   - bucket indices + degrees staged to LDS (coalesced, 1 latency round)
//   - neighbor-row loads computed from LDS => address-independent =>
//     8 loads in flight per thread per round (round = 8 edges), vs the old
//     serial idx-load -> row-load chain (2 dependent latencies PER EDGE)
//   - sa padded [32][65]: gather writes 2 lanes/bank (was 16-way conflict)
// 32 nodes per 256-thread block; double-buffered h (no in-place race).
__global__ __launch_bounds__(256) void gnn_layer_kernel(
    const float* __restrict__ h_in, float* __restrict__ h_out,
    const int* __restrict__ deg, const int* __restrict__ bucket,
    const float* __restrict__ Ws, const float* __restrict__ Wn,
    const float* __restrict__ b) {
  __shared__ float sWs[64 * 64];
  __shared__ float sWn[64 * 64];
  __shared__ float sh[32][64];
  __shared__ float sa[32][65];    // +1 pad -> conflict-free scatter writes
  __shared__ int   sbk[32][32];
  __shared__ int   sdeg[32];
  int tid = threadIdx.x;
  int base = blockIdx.x * 32;

  // ---- staging: all loads independent; single barrier publishes LDS ----
  int4 bq = reinterpret_cast<const int4*>(bucket + (size_t)base * CAP)[tid];
  if (tid < 32) sdeg[tid] = min(deg[base + tid], CAP);
  {
    const float4* Wsv = reinterpret_cast<const float4*>(Ws);
    const float4* Wnv = reinterpret_cast<const float4*>(Wn);
    float4* sWsv = reinterpret_cast<float4*>(sWs);
    float4* sWnv = reinterpret_cast<float4*>(sWn);
    for (int i = tid; i < 1024; i += 256) { sWsv[i] = Wsv[i]; sWnv[i] = Wnv[i]; }
  }
  for (int i = tid; i < 32 * 16; i += 256) {          // self rows, float4
    int r = i >> 4, q = i & 15;
    reinterpret_cast<float4*>(&sh[r][0])[q] =
        reinterpret_cast<const float4*>(h_in + (size_t)(base + r) * 64)[q];
  }
  reinterpret_cast<int4*>(&sbk[0][0])[tid] = bq;      // 1024 ints, coalesced
  __syncthreads();

  // ---- gather: all neighbor-row addresses known up front ----
  {
    int r  = tid >> 3;          // node 0..31
    int c8 = (tid & 7) * 8;     // dim chunk
    int dg = sdeg[r];
    float a0 = 0.f, a1 = 0.f, a2 = 0.f, a3 = 0.f;
    float a4 = 0.f, a5 = 0.f, a6 = 0.f, a7 = 0.f;
    for (int e0 = 0; e0 < dg; e0 += 8) {
#pragma unroll
      for (int u = 0; u < 8; u++) {
        int e = e0 + u;
        if (e < dg) {
          int s = sbk[r][e];
          const float4* hv =
              reinterpret_cast<const float4*>(h_in + (size_t)s * 64 + c8);
          float4 v0 = hv[0], v1 = hv[1];
          a0 += v0.x; a1 += v0.y; a2 += v0.z; a3 += v0.w;
          a4 += v1.x; a5 += v1.y; a6 += v1.z; a7 += v1.w;
        }
      }
    }
    sa[r][c8 + 0] = a0; sa[r][c8 + 1] = a1; sa[r][c8 + 2] = a2; sa[r][c8 + 3] = a3;
    sa[r][c8 + 4] = a4; sa[r][c8 + 5] = a5; sa[r][c8 + 6] = a6; sa[r][c8 + 7] = a7;
  }
  __syncthreads();

  // ---- dense: h_out = relu(h@Ws + agg@Wn + b) + h ----
  int j = tid & 63;   // output dim
  int g = tid >> 6;   // 4 groups x 8 rows
  float bj = b[j];
#pragma unroll
  for (int nn = 0; nn < 8; nn++) {
    int r = g * 8 + nn;
    float acc = bj;
#pragma unroll
    for (int i = 0; i < 64; i++) {
      acc = fmaf(sh[r][i], sWs[i * 64 + j], acc);
      acc = fmaf(sa[r][i], sWn[i * 64 + j], acc);
    }
    float res = ((acc > 0.f) ? acc : 0.f) + sh[r][j];
    h_out[(size_t)(base + r) * 64 + j] = res;
  }
}

// ---------------------------------------------------------------------------
// One block per graph b:
//   phase 1: lanes 0..54 of wave 0 run the MLP on final h rows -> *Wp -> reduce
//   phase 2: all 256 threads: out[b,k] = gsum + sum_j t[id_j]*Wp[55+j] + bp
__global__ __launch_bounds__(256) void out_kernel(
    const float* __restrict__ h, const float* __restrict__ t,
    const int* __restrict__ ids, const float* __restrict__ Wp,
    const float* __restrict__ bp, float* __restrict__ out,
    const float* __restrict__ W1, const float* __restrict__ b1,
    const float* __restrict__ W2, const float* __restrict__ b2,
    const float* __restrict__ W3, const float* __restrict__ b3) {
  __shared__ float sW1[64 * 32];
  __shared__ float sW2[32 * 32];
  __shared__ float sW3[32], sb1[32], sb2[32];
  __shared__ float sWp[NPER + 3];
  __shared__ float t_l[NPER];
  __shared__ float sb3, sbp, sgsum;
  int tid = threadIdx.x;
  int b = blockIdx.x;
  {
    const float4* W1v = reinterpret_cast<const float4*>(W1);
    const float4* W2v = reinterpret_cast<const float4*>(W2);
    float4* sW1v = reinterpret_cast<float4*>(sW1);
    float4* sW2v = reinterpret_cast<float4*>(sW2);
    for (int i = tid; i < 512; i += 256) sW1v[i] = W1v[i];
    for (int i = tid; i < 256; i += 256) sW2v[i] = W2v[i];
  }
  if (tid < 32) { sW3[tid] = W3[tid]; sb1[tid] = b1[tid]; sb2[tid] = b2[tid]; }
  if (tid < NPER + 3) sWp[tid] = Wp[tid];
  if (tid < NPER) t_l[tid] = t[b * NPER + tid];
  if (tid == 0) { sb3 = b3[0]; sbp = bp[0]; }
  __syncthreads();

  if (tid < 64) {     // wave 0 only
    float v = 0.f;
    if (tid < NPER) {
      float x[64];
      const float4* Xv = reinterpret_cast<const float4*>(h + (size_t)(b * NPER + tid) * 64);
#pragma unroll
      for (int i = 0; i < 16; i++) {
        float4 w = Xv[i];
        x[4 * i] = w.x; x[4 * i + 1] = w.y; x[4 * i + 2] = w.z; x[4 * i + 3] = w.w;
      }
      float a[32];
#pragma unroll
      for (int j = 0; j < 32; j++) a[j] = sb1[j];
#pragma unroll
      for (int i = 0; i < 64; i++) {
        float xi = x[i];
#pragma unroll
        for (int j = 0; j < 32; j++) a[j] = fmaf(xi, sW1[i * 32 + j], a[j]);
      }
#pragma unroll
      for (int j = 0; j < 32; j++) a[j] = (a[j] >= 0.f) ? a[j] : 0.01f * a[j];
      float c[32];
#pragma unroll
      for (int j = 0; j < 32; j++) c[j] = sb2[j];
#pragma unroll
      for (int i = 0; i < 32; i++) {
        float ai = a[i];
#pragma unroll
        for (int j = 0; j < 32; j++) c[j] = fmaf(ai, sW2[i * 32 + j], c[j]);
      }
#pragma unroll
      for (int j = 0; j < 32; j++) c[j] = (c[j] >= 0.f) ? c[j] : 0.01f * c[j];
      float r = sb3;
#pragma unroll
      for (int i = 0; i < 32; i++) r = fmaf(c[i], sW3[i], r);
      v = r * sWp[tid];
    }
#pragma unroll
    for (int off = 32; off > 0; off >>= 1) v += __shfl_down(v, off, 64);
    if (tid == 0) sgsum = v;
  }
  __syncthreads();

  // one (b,k) per thread
  const int* id = ids + ((size_t)b * KK + tid) * 3;
  int i0 = id[0], i1 = id[1], i2 = id[2];
  float acc = sgsum + sbp;
  acc = fmaf(t_l[i0], sWp[NPER + 0], acc);
  acc = fmaf(t_l[i1], sWp[NPER + 1], acc);
  acc = fmaf(t_l[i2], sWp[NPER + 2], acc);
  out[(size_t)b * KK + tid] = acc;
}

// ---------------------------------------------------------------------------
extern "C" void kernel_launch(void* const* d_in, const int* in_sizes, int n_in,
                              void* d_out, int out_size, void* d_ws, size_t ws_size,
                              hipStream_t stream) {
  const float* coords = (const float*)d_in[0];
  const int*   src    = (const int*)d_in[1];
  const int*   dst    = (const int*)d_in[2];
  const int*   ids    = (const int*)d_in[3];
  const float* We     = (const float*)d_in[4];
  const float* be     = (const float*)d_in[5];
  const float* Wself  = (const float*)d_in[6];
  const float* Wneigh = (const float*)d_in[7];
  const float* gb     = (const float*)d_in[8];
  const float* W1     = (const float*)d_in[9];
  const float* b1     = (const float*)d_in[10];
  const float* W2     = (const float*)d_in[11];
  const float* b2     = (const float*)d_in[12];
  const float* W3     = (const float*)d_in[13];
  const float* b3     = (const float*)d_in[14];
  const float* Wp     = (const float*)d_in[15];
  const float* bp     = (const float*)d_in[16];
  float* out = (float*)d_out;

  float* ws  = (float*)d_ws;
  float* h0  = ws;                         // NN*64 floats
  float* h1  = h0 + (size_t)NN * EMB;      // NN*64 floats
  float* t   = h1 + (size_t)NN * EMB;      // NN floats
  int* deg    = (int*)(t + NN);            // NN ints
  int* bucket = deg + NN;                  // NN*CAP ints (16B-aligned)

  // 1. embedding + destroy-table MLP + deg zero-init   (220 blocks x 64)
  embed_t_kernel<<<NN / 64, 64, 0, stream>>>(coords, We, be, h0, deg, t,
                                             W1, b1, W2, b2, W3, b3);
  // 2. adjacency bucket fill (one int atomic per edge)
  fill_kernel<<<EE / 256, 256, 0, stream>>>(src, dst, deg, bucket);
  // 3. three residual GNN layers, double-buffered: h0->h1->h0->h1
  const float* hin = h0;
  float* hout = h1;
  for (int l = 0; l < 3; l++) {
    gnn_layer_kernel<<<NN / 32, 256, 0, stream>>>(
        hin, hout, deg, bucket,
        Wself + l * EMB * EMB, Wneigh + l * EMB * EMB, gb + l * EMB);
    const float* tmp = hout; hout = (float*)hin; hin = tmp;
  }
  // 4. fused final MLP + graph reduce + output gather  (one block per graph)
  //    final h lives in h1 (after odd number of swaps, hin == h1)
  out_kernel<<<NB, 256, 0, stream>>>(hin, t, ids, Wp, bp, out,
                                     W1, b1, W2, b2, W3, b3);
}

// Round 10
// 226.207 us; speedup vs baseline: 2.7005x; 1.4527x over previous
//
#include <hip/hip_runtime.h>
#include <hip/hip_bf16.h>

// Problem constants (fixed by the reference)
constexpr int NB   = 256;           // graphs == grid size of mega kernel
constexpr int KK   = 256;           // destroy sets per graph
constexpr int NPER = 55;            // nodes per graph
constexpr int NN   = NB * NPER;     // 14080 nodes
constexpr int EE   = NN * 8;        // 112640 edges
constexpr int EMB  = 64;
constexpr int CAP  = 32;            // bucket capacity (verified safe)

// ---------------------------------------------------------------------------
// init: zero deg[NN] and the 2-word grid-barrier state (ws is 0xAA-poisoned).
__global__ __launch_bounds__(256) void init_kernel(int* __restrict__ deg_bar) {
  int i = blockIdx.x * 256 + threadIdx.x;
  if (i < NN + 2) deg_bar[i] = 0;
}

// ---------------------------------------------------------------------------
// Manual grid barrier: all NB blocks are co-resident (LDS forces <=2/CU,
// capacity 512 >= 256). Epoch-monotonic flag; AGENT-scope release/acquire
// makes plain h-writes visible across XCDs (L2 writeback + invalidate).
__device__ __forceinline__ void grid_barrier(int* cnt, int* flag, int ep) {
  __syncthreads();
  if (threadIdx.x == 0) {
    int old = __hip_atomic_fetch_add(cnt, 1, __ATOMIC_ACQ_REL,
                                     __HIP_MEMORY_SCOPE_AGENT);
    if (old == NB - 1) {
      __hip_atomic_store(cnt, 0, __ATOMIC_RELAXED, __HIP_MEMORY_SCOPE_AGENT);
      __hip_atomic_store(flag, ep, __ATOMIC_RELEASE, __HIP_MEMORY_SCOPE_AGENT);
    } else {
      while (__hip_atomic_load(flag, __ATOMIC_RELAXED,
                               __HIP_MEMORY_SCOPE_AGENT) < ep)
        __builtin_amdgcn_s_sleep(2);
      (void)__hip_atomic_load(flag, __ATOMIC_ACQUIRE, __HIP_MEMORY_SCOPE_AGENT);
    }
  }
  __syncthreads();
}

// ---------------------------------------------------------------------------
// Scalar MLP 64 ->(lrelu) 32 ->(lrelu) 32 -> 1, weights in LDS, fully unrolled.
__device__ __forceinline__ float mlp_lds(const float (&x)[64],
    const float* sW1, const float* sW2, const float* sW3,
    const float* sb1, const float* sb2, float b3v) {
  float a[32];
#pragma unroll
  for (int j = 0; j < 32; j++) a[j] = sb1[j];
#pragma unroll
  for (int i = 0; i < 64; i++) {
    float xi = x[i];
#pragma unroll
    for (int j = 0; j < 32; j++) a[j] = fmaf(xi, sW1[i * 32 + j], a[j]);
  }
#pragma unroll
  for (int j = 0; j < 32; j++) a[j] = (a[j] >= 0.f) ? a[j] : 0.01f * a[j];
  float c[32];
#pragma unroll
  for (int j = 0; j < 32; j++) c[j] = sb2[j];
#pragma unroll
  for (int i = 0; i < 32; i++) {
    float ai = a[i];
#pragma unroll
    for (int j = 0; j < 32; j++) c[j] = fmaf(ai, sW2[i * 32 + j], c[j]);
  }
#pragma unroll
  for (int j = 0; j < 32; j++) c[j] = (c[j] >= 0.f) ? c[j] : 0.01f * c[j];
  float r = b3v;
#pragma unroll
  for (int i = 0; i < 32; i++) r = fmaf(c[i], sW3[i], r);
  return r;
}

// ---------------------------------------------------------------------------
// One fused kernel. Block b owns graph b (nodes base..base+54).
// Phases: fill(atomics)+embed+t-MLP | GB | 3x(gather+dense) with GB between
// the global-h layers | s-MLP + reduce + out. Layer-3 h never leaves LDS.
__global__ __launch_bounds__(256) void mega_kernel(
    const float* __restrict__ coords, const int* __restrict__ src,
    const int* __restrict__ dst, const int* __restrict__ ids,
    const float* __restrict__ We, const float* __restrict__ be,
    const float* __restrict__ Wself, const float* __restrict__ Wneigh,
    const float* __restrict__ gnnb,
    const float* __restrict__ W1, const float* __restrict__ b1,
    const float* __restrict__ W2, const float* __restrict__ b2,
    const float* __restrict__ W3, const float* __restrict__ b3,
    const float* __restrict__ Wp, const float* __restrict__ bp,
    float* __restrict__ h0, float* __restrict__ h1,
    int* __restrict__ deg, int* __restrict__ bucket, int* __restrict__ bar,
    float* __restrict__ out) {
  // LDS: 16K + 16K + 14.08K + 14.96K + ~0.7K = 62.5 KB (< 64 KB static cap)
  __shared__ __align__(16) float sWs[4096];       // layer Wself | MLP W1,W2
  __shared__ __align__(16) float sWn[4096];       // layer Wneigh | MLP W3/b1/b2/b3
  __shared__ __align__(16) float sh[NPER][EMB];   // own h rows (current layer)
  __shared__ __align__(16) float uni[NPER * 68];  // sa[55][68] overlays sbk[55][33]
  __shared__ int   sdeg[NPER];
  __shared__ float t_l[NPER];
  __shared__ float sWp[NPER + 3];
  __shared__ float sgsum, sbp_s;

  float (*sa)[68] = reinterpret_cast<float (*)[68]>(uni);
  int   (*sbk)[33] = reinterpret_cast<int (*)[33]>(uni);   // 7260 B <= 14960 B

  int tid = threadIdx.x;
  int b = blockIdx.x;
  int base = b * NPER;
  int* cnt = bar;
  int* flag = bar + 1;

  // ---- phase A: stage small constants + MLP weights (into sWs/sWn overlay)
  if (tid < NPER + 3) sWp[tid] = Wp[tid];
  if (tid == 0) sbp_s = bp[0];
  for (int i = tid; i < 512; i += 256)
    reinterpret_cast<float4*>(sWs)[i] = reinterpret_cast<const float4*>(W1)[i];
  for (int i = tid; i < 256; i += 256)
    reinterpret_cast<float4*>(sWs + 2048)[i] = reinterpret_cast<const float4*>(W2)[i];
  if (tid < 32) { sWn[tid] = W3[tid]; sWn[32 + tid] = b1[tid]; sWn[64 + tid] = b2[tid]; }
  if (tid == 0) sWn[96] = b3[0];

  // ---- fill: this block's 440-edge slice (atomics fly while we compute)
  for (int i = tid; i < 8 * NPER; i += 256) {
    int e = b * (8 * NPER) + i;
    int d = dst[e];
    int s = src[e];
    int pos = atomicAdd(&deg[d], 1);
    if (pos < CAP) bucket[d * CAP + pos] = s;
  }
  __syncthreads();   // MLP weights visible for t-MLP

  // ---- embed own 55 nodes + write h0 + t-MLP (lanes 0..54 of wave 0)
  if (tid < NPER) {
    int n = base + tid;
    float cx = coords[n * 2], cy = coords[n * 2 + 1];
    float x[64];
#pragma unroll
    for (int i = 0; i < 64; i++)
      x[i] = fmaf(cx, We[i], fmaf(cy, We[64 + i], be[i]));
    float4* hv = reinterpret_cast<float4*>(h0 + (size_t)n * 64);
#pragma unroll
    for (int i = 0; i < 16; i++)
      hv[i] = make_float4(x[4 * i], x[4 * i + 1], x[4 * i + 2], x[4 * i + 3]);
#pragma unroll
    for (int i = 0; i < 64; i++) sh[tid][i] = x[i];
    t_l[tid] = mlp_lds(x, sWs, sWs + 2048, sWn, sWn + 32, sWn + 64, sWn[96]);
  }

  grid_barrier(cnt, flag, 1);        // h0 + buckets device-visible
  if (tid < NPER) sdeg[tid] = min(deg[base + tid], CAP);

  // ---- 3 GNN layers; h: h0 -> h1 -> h0 -> (LDS only)
  for (int l = 0; l < 3; l++) {
    if (l) grid_barrier(cnt, flag, l + 1);      // prev layer's h visible
    const float* hin  = (l == 1) ? h1 : h0;
    float*       hout = (l == 0) ? h1 : h0;     // unused for l==2
    const float* Wsg = Wself + l * 4096;
    const float* Wng = Wneigh + l * 4096;
    const float* gbl = gnnb + l * 64;

    // restage buckets (sbk overlays last layer's sa) + this layer's weights
    for (int i = tid; i < NPER * CAP; i += 256)
      sbk[i >> 5][i & 31] = bucket[base * CAP + i];
    for (int i = tid; i < 1024; i += 256) {
      reinterpret_cast<float4*>(sWs)[i] = reinterpret_cast<const float4*>(Wsg)[i];
      reinterpret_cast<float4*>(sWn)[i] = reinterpret_cast<const float4*>(Wng)[i];
    }
    __syncthreads();   // sbk + sdeg visible

    // gather: 4 lanes/node, 16 dims each; edge addresses known up front
    int r = tid >> 2, q = tid & 3;
    float acc[16];
    if (r < NPER) {
#pragma unroll
      for (int k = 0; k < 16; k++) acc[k] = 0.f;
      int dg = sdeg[r];
      size_t qo = (size_t)q * 16;
      for (int e0 = 0; e0 < dg; e0 += 2) {
        bool e1ok = (e0 + 1 < dg);
        int s0 = sbk[r][e0];
        int s1 = e1ok ? sbk[r][e0 + 1] : s0;
        const float4* p0 = reinterpret_cast<const float4*>(hin + (size_t)s0 * 64 + qo);
        const float4* p1 = reinterpret_cast<const float4*>(hin + (size_t)s1 * 64 + qo);
        float4 u0 = p0[0], u1 = p0[1], u2 = p0[2], u3 = p0[3];
        float4 w0 = p1[0], w1 = p1[1], w2 = p1[2], w3 = p1[3];
        acc[0] += u0.x; acc[1] += u0.y; acc[2]  += u0.z; acc[3]  += u0.w;
        acc[4] += u1.x; acc[5] += u1.y; acc[6]  += u1.z; acc[7]  += u1.w;
        acc[8] += u2.x; acc[9] += u2.y; acc[10] += u2.z; acc[11] += u2.w;
        acc[12] += u3.x; acc[13] += u3.y; acc[14] += u3.z; acc[15] += u3.w;
        if (e1ok) {
          acc[0] += w0.x; acc[1] += w0.y; acc[2]  += w0.z; acc[3]  += w0.w;
          acc[4] += w1.x; acc[5] += w1.y; acc[6]  += w1.z; acc[7]  += w1.w;
          acc[8] += w2.x; acc[9] += w2.y; acc[10] += w2.z; acc[11] += w2.w;
          acc[12] += w3.x; acc[13] += w3.y; acc[14] += w3.z; acc[15] += w3.w;
        }
      }
    }
    __syncthreads();   // all sbk reads done (sa will overwrite it)
    if (r < NPER) {
      float4* sap = reinterpret_cast<float4*>(&sa[r][0]) + q * 4;
      sap[0] = make_float4(acc[0],  acc[1],  acc[2],  acc[3]);
      sap[1] = make_float4(acc[4],  acc[5],  acc[6],  acc[7]);
      sap[2] = make_float4(acc[8],  acc[9],  acc[10], acc[11]);
      sap[3] = make_float4(acc[12], acc[13], acc[14], acc[15]);
    }
    __syncthreads();   // sa ready

    // dense: res = relu(sh@Ws + sa@Wn + b) + sh ; write global (l<2) + sh
    int j = tid & 63;
    int g = tid >> 6;
    int nrows = (g < 3) ? 14 : 13;
    float bj = gbl[j];
    float res[14];
#pragma unroll
    for (int nn = 0; nn < 14; nn++) {
      if (nn < nrows) {
        int rr = g * 14 + nn;
        float a2 = bj;
#pragma unroll
        for (int i = 0; i < 64; i++) {
          a2 = fmaf(sh[rr][i], sWs[i * 64 + j], a2);
          a2 = fmaf(sa[rr][i], sWn[i * 64 + j], a2);
        }
        res[nn] = ((a2 > 0.f) ? a2 : 0.f) + sh[rr][j];
        if (l != 2) hout[(size_t)(base + rr) * 64 + j] = res[nn];
      }
    }
    __syncthreads();   // all sh reads done
#pragma unroll
    for (int nn = 0; nn < 14; nn++)
      if (nn < nrows) sh[g * 14 + nn][j] = res[nn];
    __syncthreads();   // sh = next layer's input (or final h)
  }

  // ---- epilogue: restage MLP weights, s-MLP on final sh, reduce, out
  for (int i = tid; i < 512; i += 256)
    reinterpret_cast<float4*>(sWs)[i] = reinterpret_cast<const float4*>(W1)[i];
  for (int i = tid; i < 256; i += 256)
    reinterpret_cast<float4*>(sWs + 2048)[i] = reinterpret_cast<const float4*>(W2)[i];
  if (tid < 32) { sWn[tid] = W3[tid]; sWn[32 + tid] = b1[tid]; sWn[64 + tid] = b2[tid]; }
  if (tid == 0) sWn[96] = b3[0];
  __syncthreads();

  if (tid < 64) {      // wave 0: 55 node-MLPs + Wp-weighted reduce
    float v = 0.f;
    if (tid < NPER) {
      float x[64];
#pragma unroll
      for (int i = 0; i < 64; i++) x[i] = sh[tid][i];
      float rr = mlp_lds(x, sWs, sWs + 2048, sWn, sWn + 32, sWn + 64, sWn[96]);
      v = rr * sWp[tid];
    }
#pragma unroll
    for (int off = 32; off > 0; off >>= 1) v += __shfl_down(v, off, 64);
    if (tid == 0) sgsum = v;
  }
  __syncthreads();

  const int* id = ids + ((size_t)b * KK + tid) * 3;
  int i0 = id[0], i1 = id[1], i2 = id[2];
  float o = sgsum + sbp_s;
  o = fmaf(t_l[i0], sWp[NPER + 0], o);
  o = fmaf(t_l[i1], sWp[NPER + 1], o);
  o = fmaf(t_l[i2], sWp[NPER + 2], o);
  out[(size_t)b * KK + tid] = o;
}

// ---------------------------------------------------------------------------
extern "C" void kernel_launch(void* const* d_in, const int* in_sizes, int n_in,
                              void* d_out, int out_size, void* d_ws, size_t ws_size,
                              hipStream_t stream) {
  const float* coords = (const float*)d_in[0];
  const int*   src    = (const int*)d_in[1];
  const int*   dst    = (const int*)d_in[2];
  const int*   ids    = (const int*)d_in[3];
  const float* We     = (const float*)d_in[4];
  const float* be     = (const float*)d_in[5];
  const float* Wself  = (const float*)d_in[6];
  const float* Wneigh = (const float*)d_in[7];
  const float* gb     = (const float*)d_in[8];
  const float* W1     = (const float*)d_in[9];
  const float* b1     = (const float*)d_in[10];
  const float* W2     = (const float*)d_in[11];
  const float* b2     = (const float*)d_in[12];
  const float* W3     = (const float*)d_in[13];
  const float* b3     = (const float*)d_in[14];
  const float* Wp     = (const float*)d_in[15];
  const float* bp     = (const float*)d_in[16];
  float* out = (float*)d_out;

  float* ws = (float*)d_ws;
  float* h0 = ws;                          // NN*64 floats
  float* h1 = h0 + (size_t)NN * EMB;       // NN*64 floats
  int* deg    = (int*)(h1 + (size_t)NN * EMB);  // NN ints
  int* bar    = deg + NN;                  // 2 ints (barrier cnt/flag)
  int* bucket = bar + 2;                   // NN*CAP ints

  // 1. zero deg + barrier state (ws is 0xAA-poisoned before every call)
  init_kernel<<<(NN + 2 + 255) / 256, 256, 0, stream>>>(deg);
  // 2. everything else in one resident kernel (3 internal grid barriers)
  mega_kernel<<<NB, 256, 0, stream>>>(
      coords, src, dst, ids, We, be, Wself, Wneigh, gb,
      W1, b1, W2, b2, W3, b3, Wp, bp,
      h0, h1, deg, bucket, bar, out);
}

// Round 11
// 212.783 us; speedup vs baseline: 2.8708x; 1.0631x over previous
//
#include <hip/hip_runtime.h>
#include <hip/hip_bf16.h>

// Problem constants (fixed by the reference)
constexpr int NB   = 256;           // graphs == grid size of mega kernel
constexpr int KK   = 256;           // destroy sets per graph
constexpr int NPER = 55;            // nodes per graph
constexpr int NN   = NB * NPER;     // 14080 nodes
constexpr int EE   = NN * 8;        // 112640 edges
constexpr int EMB  = 64;
constexpr int CAP  = 32;            // bucket capacity (verified safe)

// ---------------------------------------------------------------------------
// init: zero deg[NN] + arr[NB] + flag (ws is 0xAA-poisoned before every call).
constexpr int ZERO_N = NN + NB + 16;
__global__ __launch_bounds__(256) void init_kernel(int* __restrict__ p) {
  int i = blockIdx.x * 256 + threadIdx.x;
  if (i < ZERO_N) p[i] = 0;
}

// ---------------------------------------------------------------------------
// Distributed grid barrier (all NB blocks co-resident; 62.9KB LDS -> <=2/CU,
// grid 256 <= 256 CUs, verified resident in R10).
//   arrival: ONE release store per block to its own slot (publishes h writes;
//            no same-address RMW serialization, one wbL2 per block)
//   master (block 0): 256 threads poll the 256 slots coalesced ->
//            one acquire fence (pairs with all releases) -> release flag
//   waiters: relaxed poll flag -> one acquire load (L2 inv -> fresh h)
__device__ __forceinline__ void grid_barrier(int* arr, int* flag, int ep) {
  __syncthreads();
  int tid = threadIdx.x;
  if (blockIdx.x == 0) {
    if (tid == 0)
      __hip_atomic_store(&arr[0], ep, __ATOMIC_RELEASE, __HIP_MEMORY_SCOPE_AGENT);
    while (__hip_atomic_load(&arr[tid], __ATOMIC_RELAXED,
                             __HIP_MEMORY_SCOPE_AGENT) < ep)
      __builtin_amdgcn_s_sleep(8);
    __syncthreads();              // all 256 slots observed
    if (tid == 0) {
      __threadfence();            // acquire all blocks' releases (+order flag)
      __hip_atomic_store(flag, ep, __ATOMIC_RELEASE, __HIP_MEMORY_SCOPE_AGENT);
    }
  } else {
    if (tid == 0) {
      __hip_atomic_store(&arr[blockIdx.x], ep, __ATOMIC_RELEASE,
                         __HIP_MEMORY_SCOPE_AGENT);
      while (__hip_atomic_load(flag, __ATOMIC_RELAXED,
                               __HIP_MEMORY_SCOPE_AGENT) < ep)
        __builtin_amdgcn_s_sleep(8);
      (void)__hip_atomic_load(flag, __ATOMIC_ACQUIRE, __HIP_MEMORY_SCOPE_AGENT);
    }
  }
  __syncthreads();
}

// ---------------------------------------------------------------------------
// Scalar MLP 64 ->(lrelu) 32 ->(lrelu) 32 -> 1, weights in LDS, fully unrolled.
__device__ __forceinline__ float mlp_lds(const float (&x)[64],
    const float* sW1, const float* sW2, const float* sW3,
    const float* sb1, const float* sb2, float b3v) {
  float a[32];
#pragma unroll
  for (int j = 0; j < 32; j++) a[j] = sb1[j];
#pragma unroll
  for (int i = 0; i < 64; i++) {
    float xi = x[i];
#pragma unroll
    for (int j = 0; j < 32; j++) a[j] = fmaf(xi, sW1[i * 32 + j], a[j]);
  }
#pragma unroll
  for (int j = 0; j < 32; j++) a[j] = (a[j] >= 0.f) ? a[j] : 0.01f * a[j];
  float c[32];
#pragma unroll
  for (int j = 0; j < 32; j++) c[j] = sb2[j];
#pragma unroll
  for (int i = 0; i < 32; i++) {
    float ai = a[i];
#pragma unroll
    for (int j = 0; j < 32; j++) c[j] = fmaf(ai, sW2[i * 32 + j], c[j]);
  }
#pragma unroll
  for (int j = 0; j < 32; j++) c[j] = (c[j] >= 0.f) ? c[j] : 0.01f * c[j];
  float r = b3v;
#pragma unroll
  for (int i = 0; i < 32; i++) r = fmaf(c[i], sW3[i], r);
  return r;
}

// ---------------------------------------------------------------------------
// One fused kernel. Block b owns graph b (nodes base..base+54).
// Phases: fill(atomics)+embed+t-MLP | GB | 3x(gather+dense) with GB between
// the global-h layers | s-MLP + reduce + out. Layer-3 h never leaves LDS.
__global__ __launch_bounds__(256) void mega_kernel(
    const float* __restrict__ coords, const int* __restrict__ src,
    const int* __restrict__ dst, const int* __restrict__ ids,
    const float* __restrict__ We, const float* __restrict__ be,
    const float* __restrict__ Wself, const float* __restrict__ Wneigh,
    const float* __restrict__ gnnb,
    const float* __restrict__ W1, const float* __restrict__ b1,
    const float* __restrict__ W2, const float* __restrict__ b2,
    const float* __restrict__ W3, const float* __restrict__ b3,
    const float* __restrict__ Wp, const float* __restrict__ bp,
    float* __restrict__ h0, float* __restrict__ h1,
    int* __restrict__ deg, int* __restrict__ bucket,
    int* __restrict__ arr, int* __restrict__ flag,
    float* __restrict__ out) {
  // LDS: 16K + 16K + 14.08K + 14.96K + ~0.7K = 62.5 KB (< 64 KB static cap)
  __shared__ __align__(16) float sWs[4096];       // layer Wself | MLP W1,W2
  __shared__ __align__(16) float sWn[4096];       // layer Wneigh | MLP W3/b1/b2/b3
  __shared__ __align__(16) float sh[NPER][EMB];   // own h rows (current layer)
  __shared__ __align__(16) float uni[NPER * 68];  // sa[55][68] overlays sbk[55][33]
  __shared__ int   sdeg[NPER];
  __shared__ float t_l[NPER];
  __shared__ float sWp[NPER + 3];
  __shared__ float sgsum, sbp_s;

  float (*sa)[68] = reinterpret_cast<float (*)[68]>(uni);
  int   (*sbk)[33] = reinterpret_cast<int (*)[33]>(uni);   // 7260 B <= 14960 B

  int tid = threadIdx.x;
  int b = blockIdx.x;
  int base = b * NPER;

  // ---- phase A: stage small constants + MLP weights (into sWs/sWn overlay)
  if (tid < NPER + 3) sWp[tid] = Wp[tid];
  if (tid == 0) sbp_s = bp[0];
  for (int i = tid; i < 512; i += 256)
    reinterpret_cast<float4*>(sWs)[i] = reinterpret_cast<const float4*>(W1)[i];
  for (int i = tid; i < 256; i += 256)
    reinterpret_cast<float4*>(sWs + 2048)[i] = reinterpret_cast<const float4*>(W2)[i];
  if (tid < 32) { sWn[tid] = W3[tid]; sWn[32 + tid] = b1[tid]; sWn[64 + tid] = b2[tid]; }
  if (tid == 0) sWn[96] = b3[0];

  // ---- fill: this block's 440-edge slice (atomics fly while we compute)
  for (int i = tid; i < 8 * NPER; i += 256) {
    int e = b * (8 * NPER) + i;
    int d = dst[e];
    int s = src[e];
    int pos = atomicAdd(&deg[d], 1);
    if (pos < CAP) bucket[d * CAP + pos] = s;
  }
  __syncthreads();   // MLP weights visible for t-MLP

  // ---- embed own 55 nodes + write h0 + t-MLP (lanes 0..54 of wave 0)
  if (tid < NPER) {
    int n = base + tid;
    float cx = coords[n * 2], cy = coords[n * 2 + 1];
    float x[64];
#pragma unroll
    for (int i = 0; i < 64; i++)
      x[i] = fmaf(cx, We[i], fmaf(cy, We[64 + i], be[i]));
    float4* hv = reinterpret_cast<float4*>(h0 + (size_t)n * 64);
#pragma unroll
    for (int i = 0; i < 16; i++)
      hv[i] = make_float4(x[4 * i], x[4 * i + 1], x[4 * i + 2], x[4 * i + 3]);
#pragma unroll
    for (int i = 0; i < 64; i++) sh[tid][i] = x[i];
    t_l[tid] = mlp_lds(x, sWs, sWs + 2048, sWn, sWn + 32, sWn + 64, sWn[96]);
  }

  grid_barrier(arr, flag, 1);        // h0 + buckets device-visible
  if (tid < NPER) sdeg[tid] = min(deg[base + tid], CAP);

  // ---- 3 GNN layers; h: h0 -> h1 -> h0 -> (LDS only)
  for (int l = 0; l < 3; l++) {
    if (l) grid_barrier(arr, flag, l + 1);      // prev layer's h visible
    const float* hin  = (l == 1) ? h1 : h0;
    float*       hout = (l == 0) ? h1 : h0;     // unused for l==2
    const float* Wsg = Wself + l * 4096;
    const float* Wng = Wneigh + l * 4096;
    const float* gbl = gnnb + l * 64;

    // restage buckets (sbk overlays last layer's sa) + this layer's weights
    for (int i = tid; i < NPER * CAP; i += 256)
      sbk[i >> 5][i & 31] = bucket[base * CAP + i];
    for (int i = tid; i < 1024; i += 256) {
      reinterpret_cast<float4*>(sWs)[i] = reinterpret_cast<const float4*>(Wsg)[i];
      reinterpret_cast<float4*>(sWn)[i] = reinterpret_cast<const float4*>(Wng)[i];
    }
    __syncthreads();   // sbk + sdeg visible

    // gather: 4 lanes/node, 16 dims each; edge addresses known up front
    int r = tid >> 2, q = tid & 3;
    float acc[16];
    if (r < NPER) {
#pragma unroll
      for (int k = 0; k < 16; k++) acc[k] = 0.f;
      int dg = sdeg[r];
      size_t qo = (size_t)q * 16;
      for (int e0 = 0; e0 < dg; e0 += 2) {
        bool e1ok = (e0 + 1 < dg);
        int s0 = sbk[r][e0];
        int s1 = e1ok ? sbk[r][e0 + 1] : s0;
        const float4* p0 = reinterpret_cast<const float4*>(hin + (size_t)s0 * 64 + qo);
        const float4* p1 = reinterpret_cast<const float4*>(hin + (size_t)s1 * 64 + qo);
        float4 u0 = p0[0], u1 = p0[1], u2 = p0[2], u3 = p0[3];
        float4 w0 = p1[0], w1 = p1[1], w2 = p1[2], w3 = p1[3];
        acc[0] += u0.x; acc[1] += u0.y; acc[2]  += u0.z; acc[3]  += u0.w;
        acc[4] += u1.x; acc[5] += u1.y; acc[6]  += u1.z; acc[7]  += u1.w;
        acc[8] += u2.x; acc[9] += u2.y; acc[10] += u2.z; acc[11] += u2.w;
        acc[12] += u3.x; acc[13] += u3.y; acc[14] += u3.z; acc[15] += u3.w;
        if (e1ok) {
          acc[0] += w0.x; acc[1] += w0.y; acc[2]  += w0.z; acc[3]  += w0.w;
          acc[4] += w1.x; acc[5] += w1.y; acc[6]  += w1.z; acc[7]  += w1.w;
          acc[8] += w2.x; acc[9] += w2.y; acc[10] += w2.z; acc[11] += w2.w;
          acc[12] += w3.x; acc[13] += w3.y; acc[14] += w3.z; acc[15] += w3.w;
        }
      }
    }
    __syncthreads();   // all sbk reads done (sa will overwrite it)
    if (r < NPER) {
      float4* sap = reinterpret_cast<float4*>(&sa[r][0]) + q * 4;
      sap[0] = make_float4(acc[0],  acc[1],  acc[2],  acc[3]);
      sap[1] = make_float4(acc[4],  acc[5],  acc[6],  acc[7]);
      sap[2] = make_float4(acc[8],  acc[9],  acc[10], acc[11]);
      sap[3] = make_float4(acc[12], acc[13], acc[14], acc[15]);
    }
    __syncthreads();   // sa ready

    // dense: res = relu(sh@Ws + sa@Wn + b) + sh ; write global (l<2) + sh
    int j = tid & 63;
    int g = tid >> 6;
    int nrows = (g < 3) ? 14 : 13;
    float bj = gbl[j];
    float res[14];
#pragma unroll
    for (int nn = 0; nn < 14; nn++) {
      if (nn < nrows) {
        int rr = g * 14 + nn;
        float a2 = bj;
#pragma unroll
        for (int i = 0; i < 64; i++) {
          a2 = fmaf(sh[rr][i], sWs[i * 64 + j], a2);
          a2 = fmaf(sa[rr][i], sWn[i * 64 + j], a2);
        }
        res[nn] = ((a2 > 0.f) ? a2 : 0.f) + sh[rr][j];
        if (l != 2) hout[(size_t)(base + rr) * 64 + j] = res[nn];
      }
    }
    __syncthreads();   // all sh reads done
#pragma unroll
    for (int nn = 0; nn < 14; nn++)
      if (nn < nrows) sh[g * 14 + nn][j] = res[nn];
    __syncthreads();   // sh = next layer's input (or final h)
  }

  // ---- epilogue: restage MLP weights, s-MLP on final sh, reduce, out
  for (int i = tid; i < 512; i += 256)
    reinterpret_cast<float4*>(sWs)[i] = reinterpret_cast<const float4*>(W1)[i];
  for (int i = tid; i < 256; i += 256)
    reinterpret_cast<float4*>(sWs + 2048)[i] = reinterpret_cast<const float4*>(W2)[i];
  if (tid < 32) { sWn[tid] = W3[tid]; sWn[32 + tid] = b1[tid]; sWn[64 + tid] = b2[tid]; }
  if (tid == 0) sWn[96] = b3[0];
  __syncthreads();

  if (tid < 64) {      // wave 0: 55 node-MLPs + Wp-weighted reduce
    float v = 0.f;
    if (tid < NPER) {
      float x[64];
#pragma unroll
      for (int i = 0; i < 64; i++) x[i] = sh[tid][i];
      float rr = mlp_lds(x, sWs, sWs + 2048, sWn, sWn + 32, sWn + 64, sWn[96]);
      v = rr * sWp[tid];
    }
#pragma unroll
    for (int off = 32; off > 0; off >>= 1) v += __shfl_down(v, off, 64);
    if (tid == 0) sgsum = v;
  }
  __syncthreads();

  const int* id = ids + ((size_t)b * KK + tid) * 3;
  int i0 = id[0], i1 = id[1], i2 = id[2];
  float o = sgsum + sbp_s;
  o = fmaf(t_l[i0], sWp[NPER + 0], o);
  o = fmaf(t_l[i1], sWp[NPER + 1], o);
  o = fmaf(t_l[i2], sWp[NPER + 2], o);
  out[(size_t)b * KK + tid] = o;
}

// ---------------------------------------------------------------------------
extern "C" void kernel_launch(void* const* d_in, const int* in_sizes, int n_in,
                              void* d_out, int out_size, void* d_ws, size_t ws_size,
                              hipStream_t stream) {
  const float* coords = (const float*)d_in[0];
  const int*   src    = (const int*)d_in[1];
  const int*   dst    = (const int*)d_in[2];
  const int*   ids    = (const int*)d_in[3];
  const float* We     = (const float*)d_in[4];
  const float* be     = (const float*)d_in[5];
  const float* Wself  = (const float*)d_in[6];
  const float* Wneigh = (const float*)d_in[7];
  const float* gb     = (const float*)d_in[8];
  const float* W1     = (const float*)d_in[9];
  const float* b1     = (const float*)d_in[10];
  const float* W2     = (const float*)d_in[11];
  const float* b2     = (const float*)d_in[12];
  const float* W3     = (const float*)d_in[13];
  const float* b3     = (const float*)d_in[14];
  const float* Wp     = (const float*)d_in[15];
  const float* bp     = (const float*)d_in[16];
  float* out = (float*)d_out;

  float* ws = (float*)d_ws;
  float* h0 = ws;                          // NN*64 floats
  float* h1 = h0 + (size_t)NN * EMB;       // NN*64 floats
  int* deg    = (int*)(h1 + (size_t)NN * EMB);  // NN ints
  int* arr    = deg + NN;                  // NB arrival slots
  int* flag   = arr + NB;                  // release flag (+pad)
  int* bucket = flag + 16;                 // NN*CAP ints

  // 1. zero deg + arrival slots + flag (ws is 0xAA-poisoned every call)
  init_kernel<<<(ZERO_N + 255) / 256, 256, 0, stream>>>(deg);
  // 2. everything else in one resident kernel (3 internal grid barriers)
  mega_kernel<<<NB, 256, 0, stream>>>(
      coords, src, dst, ids, We, be, Wself, Wneigh, gb,
      W1, b1, W2, b2, W3, b3, Wp, bp,
      h0, h1, deg, bucket, arr, flag, out);
}

// Round 12
// 185.510 us; speedup vs baseline: 3.2929x; 1.1470x over previous
//
#include <hip/hip_runtime.h>
#include <hip/hip_bf16.h>

// Problem constants (fixed by the reference)
constexpr int NB   = 256;           // graphs == grid size of mega kernel
constexpr int KK   = 256;           // destroy sets per graph
constexpr int NPER = 55;            // nodes per graph
constexpr int NN   = NB * NPER;     // 14080 nodes
constexpr int EMB  = 64;
constexpr int CAP  = 32;            // bucket capacity (verified safe)
constexpr int NT   = 512;           // threads per block (8 waves/CU)

// ---------------------------------------------------------------------------
// init: zero deg[NN] + arr[NB] + flag (ws is 0xAA-poisoned before every call).
constexpr int ZERO_N = NN + NB + 16;
__global__ __launch_bounds__(256) void init_kernel(int* __restrict__ p) {
  int i = blockIdx.x * 256 + threadIdx.x;
  if (i < ZERO_N) p[i] = 0;
}

// ---------------------------------------------------------------------------
// Distributed grid barrier (R11-proven): one release store per block,
// master (block 0) polls slots coalesced, one fence pair per block.
__device__ __forceinline__ void grid_barrier(int* arr, int* flag, int ep) {
  __syncthreads();
  int tid = threadIdx.x;
  if (blockIdx.x == 0) {
    if (tid == 0)
      __hip_atomic_store(&arr[0], ep, __ATOMIC_RELEASE, __HIP_MEMORY_SCOPE_AGENT);
    if (tid < NB) {
      while (__hip_atomic_load(&arr[tid], __ATOMIC_RELAXED,
                               __HIP_MEMORY_SCOPE_AGENT) < ep)
        __builtin_amdgcn_s_sleep(8);
    }
    __syncthreads();              // all 256 slots observed
    if (tid == 0) {
      __threadfence();            // acquire all blocks' releases (+order flag)
      __hip_atomic_store(flag, ep, __ATOMIC_RELEASE, __HIP_MEMORY_SCOPE_AGENT);
    }
  } else {
    if (tid == 0) {
      __hip_atomic_store(&arr[blockIdx.x], ep, __ATOMIC_RELEASE,
                         __HIP_MEMORY_SCOPE_AGENT);
      while (__hip_atomic_load(flag, __ATOMIC_RELAXED,
                               __HIP_MEMORY_SCOPE_AGENT) < ep)
        __builtin_amdgcn_s_sleep(8);
      (void)__hip_atomic_load(flag, __ATOMIC_ACQUIRE, __HIP_MEMORY_SCOPE_AGENT);
    }
  }
  __syncthreads();
}

// ---------------------------------------------------------------------------
// Scalar MLP 64 ->(lrelu) 32 ->(lrelu) 32 -> 1, weights in LDS, fully unrolled.
__device__ __forceinline__ float mlp_lds(const float (&x)[64],
    const float* sW1, const float* sW2, const float* sW3,
    const float* sb1, const float* sb2, float b3v) {
  float a[32];
#pragma unroll
  for (int j = 0; j < 32; j++) a[j] = sb1[j];
#pragma unroll
  for (int i = 0; i < 64; i++) {
    float xi = x[i];
#pragma unroll
    for (int j = 0; j < 32; j++) a[j] = fmaf(xi, sW1[i * 32 + j], a[j]);
  }
#pragma unroll
  for (int j = 0; j < 32; j++) a[j] = (a[j] >= 0.f) ? a[j] : 0.01f * a[j];
  float c[32];
#pragma unroll
  for (int j = 0; j < 32; j++) c[j] = sb2[j];
#pragma unroll
  for (int i = 0; i < 32; i++) {
    float ai = a[i];
#pragma unroll
    for (int j = 0; j < 32; j++) c[j] = fmaf(ai, sW2[i * 32 + j], c[j]);
  }
#pragma unroll
  for (int j = 0; j < 32; j++) c[j] = (c[j] >= 0.f) ? c[j] : 0.01f * c[j];
  float r = b3v;
#pragma unroll
  for (int i = 0; i < 32; i++) r = fmaf(c[i], sW3[i], r);
  return r;
}

// ---------------------------------------------------------------------------
__global__ __launch_bounds__(NT) void mega_kernel(
    const float* __restrict__ coords, const int* __restrict__ src,
    const int* __restrict__ dst, const int* __restrict__ ids,
    const float* __restrict__ We, const float* __restrict__ be,
    const float* __restrict__ Wself, const float* __restrict__ Wneigh,
    const float* __restrict__ gnnb,
    const float* __restrict__ W1, const float* __restrict__ b1,
    const float* __restrict__ W2, const float* __restrict__ b2,
    const float* __restrict__ W3, const float* __restrict__ b3,
    const float* __restrict__ Wp, const float* __restrict__ bp,
    float* __restrict__ h0, float* __restrict__ h1,
    int* __restrict__ deg, int* __restrict__ bucket,
    int* __restrict__ arr, int* __restrict__ flag,
    float* __restrict__ out) {
  // LDS: 16K + 16K + 14.08K + 14.08K + ~0.7K = 60.9 KB (1 block/CU, 8 waves)
  __shared__ __align__(16) float sWs[4096];       // layer Wself | MLP W1,W2
  __shared__ __align__(16) float sWn[4096];       // layer Wneigh | MLP W3/b1/b2/b3
  __shared__ __align__(16) float sh[NPER][EMB];   // own h rows (current layer)
  __shared__ __align__(16) float uni[NPER * EMB]; // sa[55][64] overlays sbk[55][32]
  __shared__ int   sdeg[NPER];
  __shared__ float t_l[NPER];
  __shared__ float sWp[NPER + 3];
  __shared__ float sgsum, sbp_s;

  float (*sa)[EMB] = reinterpret_cast<float (*)[EMB]>(uni);
  int   (*sbk)[CAP] = reinterpret_cast<int (*)[CAP]>(uni);  // 7040B <= 14080B

  int tid = threadIdx.x;
  int b = blockIdx.x;
  int base = b * NPER;

  // ---- prologue: MLP weights + constants + edge fill -----------------------
  if (tid < NPER + 3) sWp[tid] = Wp[tid];
  if (tid == 0) sbp_s = bp[0];
  if (tid < 512)
    reinterpret_cast<float4*>(sWs)[tid] = reinterpret_cast<const float4*>(W1)[tid];
  if (tid < 256)
    reinterpret_cast<float4*>(sWs + 2048)[tid] = reinterpret_cast<const float4*>(W2)[tid];
  if (tid < 32) { sWn[tid] = W3[tid]; sWn[32 + tid] = b1[tid]; sWn[64 + tid] = b2[tid]; }
  if (tid == 0) sWn[96] = b3[0];
  if (tid < 8 * NPER) {                    // 440 edges of this graph
    int e = b * (8 * NPER) + tid;
    int d = dst[e];
    int s = src[e];
    int pos = atomicAdd(&deg[d], 1);
    if (pos < CAP) bucket[d * CAP + pos] = s;
  }
  __syncthreads();   // MLP weights visible

  // ---- embed own 55 nodes + h0 + t-MLP (wave 0) ----------------------------
  if (tid < NPER) {
    int n = base + tid;
    float cx = coords[n * 2], cy = coords[n * 2 + 1];
    float x[64];
#pragma unroll
    for (int i = 0; i < 64; i++)
      x[i] = fmaf(cx, We[i], fmaf(cy, We[64 + i], be[i]));
    float4* hv = reinterpret_cast<float4*>(h0 + (size_t)n * 64);
#pragma unroll
    for (int i = 0; i < 16; i++)
      hv[i] = make_float4(x[4 * i], x[4 * i + 1], x[4 * i + 2], x[4 * i + 3]);
#pragma unroll
    for (int i = 0; i < 64; i++) sh[tid][i] = x[i];
    t_l[tid] = mlp_lds(x, sWs, sWs + 2048, sWn, sWn + 32, sWn + 64, sWn[96]);
  }
  __syncthreads();   // t-MLP done reading sWs/sWn

  // stage layer-0 weights BEFORE barrier (immutable; overlaps arrival skew)
  {
    const float4* Wsv = reinterpret_cast<const float4*>(Wself);
    const float4* Wnv = reinterpret_cast<const float4*>(Wneigh);
    for (int i = tid; i < 1024; i += NT) {
      reinterpret_cast<float4*>(sWs)[i] = Wsv[i];
      reinterpret_cast<float4*>(sWn)[i] = Wnv[i];
    }
  }

  grid_barrier(arr, flag, 1);        // h0 + buckets device-visible
  if (tid < NPER) sdeg[tid] = min(deg[base + tid], CAP);

  // ---- 3 GNN layers; h: h0 -> h1 -> h0 -> (LDS only) -----------------------
  for (int l = 0; l < 3; l++) {
    const float* hin  = (l == 1) ? h1 : h0;
    float*       hout = (l == 0) ? h1 : h0;     // unused for l==2
    const float* gbl = gnnb + l * 64;

    // stage this block's buckets into LDS (l=0: after barrier; l>0: staged
    // pre-barrier below). int4-coalesced, 440 int4 total.
    if (l == 0) {
      for (int i = tid; i < NPER * CAP / 4; i += NT)
        reinterpret_cast<int4*>(uni)[i] =
            reinterpret_cast<const int4*>(bucket + (size_t)base * CAP)[i];
      __syncthreads();
    }

    // ---- gather: 8 lanes/node, 8 dims each; addresses known up front ----
    int r = tid >> 3, o = tid & 7;
    float a0 = 0.f, a1 = 0.f, a2 = 0.f, a3 = 0.f;
    float a4 = 0.f, a5 = 0.f, a6 = 0.f, a7 = 0.f;
    if (r < NPER) {
      int dg = sdeg[r];
      size_t oo = (size_t)o * 8;
      for (int e0 = 0; e0 < dg; e0 += 2) {
        bool ok1 = (e0 + 1 < dg);
        int s0 = sbk[r][e0];
        int s1 = ok1 ? sbk[r][e0 + 1] : s0;
        const float4* p0 = reinterpret_cast<const float4*>(hin + (size_t)s0 * 64 + oo);
        const float4* p1 = reinterpret_cast<const float4*>(hin + (size_t)s1 * 64 + oo);
        float4 u0 = p0[0], u1 = p0[1];
        float4 w0 = p1[0], w1 = p1[1];
        a0 += u0.x; a1 += u0.y; a2 += u0.z; a3 += u0.w;
        a4 += u1.x; a5 += u1.y; a6 += u1.z; a7 += u1.w;
        if (ok1) {
          a0 += w0.x; a1 += w0.y; a2 += w0.z; a3 += w0.w;
          a4 += w1.x; a5 += w1.y; a6 += w1.z; a7 += w1.w;
        }
      }
    }
    __syncthreads();   // all sbk reads done (sa overwrites the same LDS)
    if (r < NPER) {
      float4* sap = reinterpret_cast<float4*>(&sa[r][o * 8]);
      sap[0] = make_float4(a0, a1, a2, a3);
      sap[1] = make_float4(a4, a5, a6, a7);
    }
    __syncthreads();   // sa ready

    // ---- dense: chunk-hoisted weights in regs, broadcast b128 sh/sa ----
    // acc = sh@Ws + sa@Wn + b ; res = relu(acc) + sh ; 7 rows per wave-group
    int j = tid & 63;
    int g = tid >> 6;                       // 0..7
    int nrows = (g < 7) ? 7 : 6;            // 7*7+6 = 55
    int rbase = g * 7;
    float bj = gbl[j];
    float acc[7];
#pragma unroll
    for (int nn = 0; nn < 7; nn++) acc[nn] = bj;
#pragma unroll
    for (int c = 0; c < 16; c++) {
      int ib = c * 4;
      float w0 = sWs[(ib + 0) * 64 + j], w1 = sWs[(ib + 1) * 64 + j];
      float w2 = sWs[(ib + 2) * 64 + j], w3 = sWs[(ib + 3) * 64 + j];
      float v0 = sWn[(ib + 0) * 64 + j], v1 = sWn[(ib + 1) * 64 + j];
      float v2 = sWn[(ib + 2) * 64 + j], v3 = sWn[(ib + 3) * 64 + j];
#pragma unroll
      for (int nn = 0; nn < 7; nn++) {
        if (nn < nrows) {
          int rr = rbase + nn;
          float4 hs = *reinterpret_cast<const float4*>(&sh[rr][ib]);
          float4 as = *reinterpret_cast<const float4*>(&sa[rr][ib]);
          float t = acc[nn];
          t = fmaf(hs.x, w0, t); t = fmaf(hs.y, w1, t);
          t = fmaf(hs.z, w2, t); t = fmaf(hs.w, w3, t);
          t = fmaf(as.x, v0, t); t = fmaf(as.y, v1, t);
          t = fmaf(as.z, v2, t); t = fmaf(as.w, v3, t);
          acc[nn] = t;
        }
      }
    }
    float res[7];
#pragma unroll
    for (int nn = 0; nn < 7; nn++) {
      if (nn < nrows) {
        int rr = rbase + nn;
        res[nn] = ((acc[nn] > 0.f) ? acc[nn] : 0.f) + sh[rr][j];
        if (l != 2) hout[(size_t)(base + rr) * 64 + j] = res[nn];
      }
    }
    __syncthreads();   // all sh reads done
#pragma unroll
    for (int nn = 0; nn < 7; nn++)
      if (nn < nrows) sh[rbase + nn][j] = res[nn];
    __syncthreads();   // sh = next layer's input (or final h)

    // ---- pre-barrier staging for next layer (immutable data, warm L2) ----
    if (l < 2) {
      for (int i = tid; i < NPER * CAP / 4; i += NT)
        reinterpret_cast<int4*>(uni)[i] =
            reinterpret_cast<const int4*>(bucket + (size_t)base * CAP)[i];
      const float4* Wsv = reinterpret_cast<const float4*>(Wself + (l + 1) * 4096);
      const float4* Wnv = reinterpret_cast<const float4*>(Wneigh + (l + 1) * 4096);
      for (int i = tid; i < 1024; i += NT) {
        reinterpret_cast<float4*>(sWs)[i] = Wsv[i];
        reinterpret_cast<float4*>(sWn)[i] = Wnv[i];
      }
      grid_barrier(arr, flag, l + 2);   // prev layer's h now visible
    }
  }

  // ---- epilogue: restage MLP weights, s-MLP on final sh, reduce, out -------
  if (tid < 512)
    reinterpret_cast<float4*>(sWs)[tid] = reinterpret_cast<const float4*>(W1)[tid];
  if (tid < 256)
    reinterpret_cast<float4*>(sWs + 2048)[tid] = reinterpret_cast<const float4*>(W2)[tid];
  if (tid < 32) { sWn[tid] = W3[tid]; sWn[32 + tid] = b1[tid]; sWn[64 + tid] = b2[tid]; }
  if (tid == 0) sWn[96] = b3[0];
  __syncthreads();

  if (tid < 64) {      // wave 0: 55 node-MLPs + Wp-weighted reduce
    float v = 0.f;
    if (tid < NPER) {
      float x[64];
#pragma unroll
      for (int i = 0; i < 64; i++) x[i] = sh[tid][i];
      float rr = mlp_lds(x, sWs, sWs + 2048, sWn, sWn + 32, sWn + 64, sWn[96]);
      v = rr * sWp[tid];
    }
#pragma unroll
    for (int off = 32; off > 0; off >>= 1) v += __shfl_down(v, off, 64);
    if (tid == 0) sgsum = v;
  }
  __syncthreads();

  if (tid < KK) {
    const int* id = ids + ((size_t)b * KK + tid) * 3;
    int i0 = id[0], i1 = id[1], i2 = id[2];
    float o = sgsum + sbp_s;
    o = fmaf(t_l[i0], sWp[NPER + 0], o);
    o = fmaf(t_l[i1], sWp[NPER + 1], o);
    o = fmaf(t_l[i2], sWp[NPER + 2], o);
    out[(size_t)b * KK + tid] = o;
  }
}

// ---------------------------------------------------------------------------
extern "C" void kernel_launch(void* const* d_in, const int* in_sizes, int n_in,
                              void* d_out, int out_size, void* d_ws, size_t ws_size,
                              hipStream_t stream) {
  const float* coords = (const float*)d_in[0];
  const int*   src    = (const int*)d_in[1];
  const int*   dst    = (const int*)d_in[2];
  const int*   ids    = (const int*)d_in[3];
  const float* We     = (const float*)d_in[4];
  const float* be     = (const float*)d_in[5];
  const float* Wself  = (const float*)d_in[6];
  const float* Wneigh = (const float*)d_in[7];
  const float* gb     = (const float*)d_in[8];
  const float* W1     = (const float*)d_in[9];
  const float* b1     = (const float*)d_in[10];
  const float* W2     = (const float*)d_in[11];
  const float* b2     = (const float*)d_in[12];
  const float* W3     = (const float*)d_in[13];
  const float* b3     = (const float*)d_in[14];
  const float* Wp     = (const float*)d_in[15];
  const float* bp     = (const float*)d_in[16];
  float* out = (float*)d_out;

  float* ws = (float*)d_ws;
  float* h0 = ws;                          // NN*64 floats
  float* h1 = h0 + (size_t)NN * EMB;       // NN*64 floats
  int* deg    = (int*)(h1 + (size_t)NN * EMB);  // NN ints
  int* arr    = deg + NN;                  // NB arrival slots
  int* flag   = arr + NB;                  // release flag (+pad)
  int* bucket = flag + 16;                 // NN*CAP ints

  // 1. zero deg + arrival slots + flag (ws is 0xAA-poisoned every call)
  init_kernel<<<(ZERO_N + 255) / 256, 256, 0, stream>>>(deg);
  // 2. everything else in one resident kernel (3 internal grid barriers)
  mega_kernel<<<NB, NT, 0, stream>>>(
      coords, src, dst, ids, We, be, Wself, Wneigh, gb,
      W1, b1, W2, b2, W3, b3, Wp, bp,
      h0, h1, deg, bucket, arr, flag, out);
}

// Round 13
// 172.725 us; speedup vs baseline: 3.5366x; 1.0740x over previous
//
#include <hip/hip_runtime.h>
#include <hip/hip_bf16.h>

// Problem constants (fixed by the reference)
constexpr int NB   = 256;           // graphs == grid size of mega kernel
constexpr int KK   = 256;           // destroy sets per graph
constexpr int NPER = 55;            // nodes per graph
constexpr int NN   = NB * NPER;     // 14080 nodes
constexpr int EMB  = 64;
constexpr int CAP  = 32;            // bucket capacity (verified safe)
constexpr int NT   = 512;           // threads per block (8 waves/CU)

// ---------------------------------------------------------------------------
// Device-coherent (LLC) scalar ops: RELAXED + AGENT scope -> sc0/sc1 flagged,
// bypass L1/L2 -> no barrier cache maintenance needed anywhere.
using ull = unsigned long long;
__device__ __forceinline__ void st_f1(float* p, float x) {
  union { float f; unsigned u; } v; v.f = x;
  __hip_atomic_store((unsigned*)p, v.u, __ATOMIC_RELAXED, __HIP_MEMORY_SCOPE_AGENT);
}
__device__ __forceinline__ void st_f2(float* p, float x, float y) {
  union { float f[2]; ull u; } v; v.f[0] = x; v.f[1] = y;
  __hip_atomic_store((ull*)p, v.u, __ATOMIC_RELAXED, __HIP_MEMORY_SCOPE_AGENT);
}
__device__ __forceinline__ float2 ld_f2(const float* p) {
  union { ull u; float f[2]; } v;
  v.u = __hip_atomic_load((const ull*)p, __ATOMIC_RELAXED, __HIP_MEMORY_SCOPE_AGENT);
  return make_float2(v.f[0], v.f[1]);
}
__device__ __forceinline__ int ld_i1(const int* p) {
  return __hip_atomic_load(p, __ATOMIC_RELAXED, __HIP_MEMORY_SCOPE_AGENT);
}
__device__ __forceinline__ void st_i1(int* p, int x) {
  __hip_atomic_store(p, x, __ATOMIC_RELAXED, __HIP_MEMORY_SCOPE_AGENT);
}
__device__ __forceinline__ int2 ld_i2(const int* p) {
  union { ull u; int i[2]; } v;
  v.u = __hip_atomic_load((const ull*)p, __ATOMIC_RELAXED, __HIP_MEMORY_SCOPE_AGENT);
  return make_int2(v.i[0], v.i[1]);
}

// ---------------------------------------------------------------------------
// init: zero deg[NN] + arr[NB] + flag (ws is 0xAA-poisoned before every call).
constexpr int ZERO_N = NN + NB + 16;
__global__ __launch_bounds__(256) void init_kernel(int* __restrict__ p) {
  int i = blockIdx.x * 256 + threadIdx.x;
  if (i < ZERO_N) p[i] = 0;
}

// ---------------------------------------------------------------------------
// Fence-FREE grid barrier: all cross-block data uses LLC-coherent sc ops, so
// no wbL2/invL2 is required. __syncthreads() drains each wave's vmcnt (stores
// acked at LLC) before the arrival store. L2-cached read-only data (weights,
// sbk staging) stays WARM across barriers.
__device__ __forceinline__ void grid_barrier(int* arr, int* flag, int ep) {
  __syncthreads();                 // all waves' sc-stores drained (vmcnt)
  int tid = threadIdx.x;
  if (blockIdx.x == 0) {
    if (tid == 0) st_i1(&arr[0], ep);
    if (tid < NB) {
      while (ld_i1(&arr[tid]) < ep) __builtin_amdgcn_s_sleep(8);
    }
    __syncthreads();               // all 256 slots observed
    if (tid == 0) st_i1(flag, ep);
  } else {
    if (tid == 0) {
      st_i1(&arr[blockIdx.x], ep);
      while (ld_i1(flag) < ep) __builtin_amdgcn_s_sleep(8);
    }
  }
  __syncthreads();
}

// ---------------------------------------------------------------------------
// Scalar MLP 64 ->(lrelu) 32 ->(lrelu) 32 -> 1, weights in LDS, fully unrolled.
__device__ __forceinline__ float mlp_lds(const float (&x)[64],
    const float* sW1, const float* sW2, const float* sW3,
    const float* sb1, const float* sb2, float b3v) {
  float a[32];
#pragma unroll
  for (int j = 0; j < 32; j++) a[j] = sb1[j];
#pragma unroll
  for (int i = 0; i < 64; i++) {
    float xi = x[i];
#pragma unroll
    for (int j = 0; j < 32; j++) a[j] = fmaf(xi, sW1[i * 32 + j], a[j]);
  }
#pragma unroll
  for (int j = 0; j < 32; j++) a[j] = (a[j] >= 0.f) ? a[j] : 0.01f * a[j];
  float c[32];
#pragma unroll
  for (int j = 0; j < 32; j++) c[j] = sb2[j];
#pragma unroll
  for (int i = 0; i < 32; i++) {
    float ai = a[i];
#pragma unroll
    for (int j = 0; j < 32; j++) c[j] = fmaf(ai, sW2[i * 32 + j], c[j]);
  }
#pragma unroll
  for (int j = 0; j < 32; j++) c[j] = (c[j] >= 0.f) ? c[j] : 0.01f * c[j];
  float r = b3v;
#pragma unroll
  for (int i = 0; i < 32; i++) r = fmaf(c[i], sW3[i], r);
  return r;
}

// ---------------------------------------------------------------------------
__global__ __launch_bounds__(NT) void mega_kernel(
    const float* __restrict__ coords, const int* __restrict__ src,
    const int* __restrict__ dst, const int* __restrict__ ids,
    const float* __restrict__ We, const float* __restrict__ be,
    const float* __restrict__ Wself, const float* __restrict__ Wneigh,
    const float* __restrict__ gnnb,
    const float* __restrict__ W1, const float* __restrict__ b1,
    const float* __restrict__ W2, const float* __restrict__ b2,
    const float* __restrict__ W3, const float* __restrict__ b3,
    const float* __restrict__ Wp, const float* __restrict__ bp,
    float* __restrict__ h0, float* __restrict__ h1,
    int* __restrict__ deg, int* __restrict__ bucket,
    int* __restrict__ arr, int* __restrict__ flag,
    float* __restrict__ out) {
  // LDS: 16K + 16K + 14.08K + 14.08K + ~0.7K = 60.9 KB (1 block/CU, 8 waves)
  __shared__ __align__(16) float sWs[4096];       // layer Wself | MLP W1,W2
  __shared__ __align__(16) float sWn[4096];       // layer Wneigh | MLP W3/b1/b2/b3
  __shared__ __align__(16) float sh[NPER][EMB];   // own h rows (current layer)
  __shared__ __align__(16) float uni[NPER * EMB]; // sa[55][64] overlays sbk[55][32]
  __shared__ int   sdeg[NPER];
  __shared__ float t_l[NPER];
  __shared__ float sWp[NPER + 3];
  __shared__ float sgsum, sbp_s;

  float (*sa)[EMB] = reinterpret_cast<float (*)[EMB]>(uni);
  int   (*sbk)[CAP] = reinterpret_cast<int (*)[CAP]>(uni);  // 7040B <= 14080B

  int tid = threadIdx.x;
  int b = blockIdx.x;
  int base = b * NPER;

  // ---- prologue: MLP weights + constants + edge fill -----------------------
  if (tid < NPER + 3) sWp[tid] = Wp[tid];
  if (tid == 0) sbp_s = bp[0];
  if (tid < 512)
    reinterpret_cast<float4*>(sWs)[tid] = reinterpret_cast<const float4*>(W1)[tid];
  if (tid < 256)
    reinterpret_cast<float4*>(sWs + 2048)[tid] = reinterpret_cast<const float4*>(W2)[tid];
  if (tid < 32) { sWn[tid] = W3[tid]; sWn[32 + tid] = b1[tid]; sWn[64 + tid] = b2[tid]; }
  if (tid == 0) sWn[96] = b3[0];
  if (tid < 8 * NPER) {                    // 440 edges of this graph's slice
    int e = b * (8 * NPER) + tid;
    int d = dst[e];
    int s = src[e];
    int pos = atomicAdd(&deg[d], 1);       // device RMW: LLC-coherent
    if (pos < CAP) st_i1(&bucket[d * CAP + pos], s);   // sc store (cross-block)
  }
  __syncthreads();   // MLP weights visible

  // ---- embed own 55 nodes + h0 (sc stores) + t-MLP (wave 0) ----------------
  if (tid < NPER) {
    int n = base + tid;
    float cx = coords[n * 2], cy = coords[n * 2 + 1];
    float x[64];
#pragma unroll
    for (int i = 0; i < 64; i++)
      x[i] = fmaf(cx, We[i], fmaf(cy, We[64 + i], be[i]));
    float* hv = h0 + (size_t)n * 64;
#pragma unroll
    for (int i = 0; i < 32; i++) st_f2(hv + 2 * i, x[2 * i], x[2 * i + 1]);
#pragma unroll
    for (int i = 0; i < 64; i++) sh[tid][i] = x[i];
    t_l[tid] = mlp_lds(x, sWs, sWs + 2048, sWn, sWn + 32, sWn + 64, sWn[96]);
  }
  __syncthreads();   // t-MLP done reading sWs/sWn

  // stage layer-0 weights BEFORE barrier (immutable; overlaps arrival skew)
  {
    const float4* Wsv = reinterpret_cast<const float4*>(Wself);
    const float4* Wnv = reinterpret_cast<const float4*>(Wneigh);
    for (int i = tid; i < 1024; i += NT) {
      reinterpret_cast<float4*>(sWs)[i] = Wsv[i];
      reinterpret_cast<float4*>(sWn)[i] = Wnv[i];
    }
  }

  grid_barrier(arr, flag, 1);        // h0 + buckets LLC-visible
  if (tid < NPER) sdeg[tid] = min(ld_i1(&deg[base + tid]), CAP);

  // ---- 3 GNN layers; h: h0 -> h1 -> h0 -> (LDS only) -----------------------
  for (int l = 0; l < 3; l++) {
    const float* hin  = (l == 1) ? h1 : h0;
    float*       hout = (l == 0) ? h1 : h0;     // unused for l==2
    const float* gbl = gnnb + l * 64;

    // stage this block's buckets into LDS (sc loads; l>0 staged pre-barrier)
    if (l == 0) {
      for (int i = tid; i < NPER * CAP / 2; i += NT) {
        int2 v = ld_i2(bucket + (size_t)base * CAP + 2 * i);
        sbk[0][2 * i] = v.x; sbk[0][2 * i + 1] = v.y;
      }
      __syncthreads();
    }

    // ---- gather: 8 lanes/node, 8 dims each; sc float2 loads (LLC) ----
    int r = tid >> 3, o = tid & 7;
    float a0 = 0.f, a1 = 0.f, a2 = 0.f, a3 = 0.f;
    float a4 = 0.f, a5 = 0.f, a6 = 0.f, a7 = 0.f;
    if (r < NPER) {
      int dg = sdeg[r];
      size_t oo = (size_t)o * 8;
      for (int e0 = 0; e0 < dg; e0 += 2) {
        bool ok1 = (e0 + 1 < dg);
        int s0 = sbk[r][e0];
        int s1 = ok1 ? sbk[r][e0 + 1] : s0;
        const float* p0 = hin + (size_t)s0 * 64 + oo;
        const float* p1 = hin + (size_t)s1 * 64 + oo;
        float2 u0 = ld_f2(p0), u1 = ld_f2(p0 + 2), u2 = ld_f2(p0 + 4), u3 = ld_f2(p0 + 6);
        float2 w0 = ld_f2(p1), w1 = ld_f2(p1 + 2), w2 = ld_f2(p1 + 4), w3 = ld_f2(p1 + 6);
        a0 += u0.x; a1 += u0.y; a2 += u1.x; a3 += u1.y;
        a4 += u2.x; a5 += u2.y; a6 += u3.x; a7 += u3.y;
        if (ok1) {
          a0 += w0.x; a1 += w0.y; a2 += w1.x; a3 += w1.y;
          a4 += w2.x; a5 += w2.y; a6 += w3.x; a7 += w3.y;
        }
      }
    }
    __syncthreads();   // all sbk reads done (sa overwrites the same LDS)
    if (r < NPER) {
      float4* sap = reinterpret_cast<float4*>(&sa[r][o * 8]);
      sap[0] = make_float4(a0, a1, a2, a3);
      sap[1] = make_float4(a4, a5, a6, a7);
    }
    __syncthreads();   // sa ready

    // ---- dense: chunk-hoisted weights in regs, broadcast b128 sh/sa ----
    int j = tid & 63;
    int g = tid >> 6;                       // 0..7
    int nrows = (g < 7) ? 7 : 6;            // 7*7+6 = 55
    int rbase = g * 7;
    float bj = gbl[j];
    float acc[7];
#pragma unroll
    for (int nn = 0; nn < 7; nn++) acc[nn] = bj;
#pragma unroll
    for (int c = 0; c < 16; c++) {
      int ib = c * 4;
      float w0 = sWs[(ib + 0) * 64 + j], w1 = sWs[(ib + 1) * 64 + j];
      float w2 = sWs[(ib + 2) * 64 + j], w3 = sWs[(ib + 3) * 64 + j];
      float v0 = sWn[(ib + 0) * 64 + j], v1 = sWn[(ib + 1) * 64 + j];
      float v2 = sWn[(ib + 2) * 64 + j], v3 = sWn[(ib + 3) * 64 + j];
#pragma unroll
      for (int nn = 0; nn < 7; nn++) {
        if (nn < nrows) {
          int rr = rbase + nn;
          float4 hs = *reinterpret_cast<const float4*>(&sh[rr][ib]);
          float4 as = *reinterpret_cast<const float4*>(&sa[rr][ib]);
          float t = acc[nn];
          t = fmaf(hs.x, w0, t); t = fmaf(hs.y, w1, t);
          t = fmaf(hs.z, w2, t); t = fmaf(hs.w, w3, t);
          t = fmaf(as.x, v0, t); t = fmaf(as.y, v1, t);
          t = fmaf(as.z, v2, t); t = fmaf(as.w, v3, t);
          acc[nn] = t;
        }
      }
    }
    float res[7];
#pragma unroll
    for (int nn = 0; nn < 7; nn++) {
      if (nn < nrows) {
        int rr = rbase + nn;
        res[nn] = ((acc[nn] > 0.f) ? acc[nn] : 0.f) + sh[rr][j];
        if (l != 2) st_f1(&hout[(size_t)(base + rr) * 64 + j], res[nn]);  // sc
      }
    }
    __syncthreads();   // all sh reads done
#pragma unroll
    for (int nn = 0; nn < 7; nn++)
      if (nn < nrows) sh[rbase + nn][j] = res[nn];
    __syncthreads();   // sh = next layer's input (or final h)

    // ---- pre-barrier staging for next layer (bucket sc; weights warm L2) ----
    if (l < 2) {
      for (int i = tid; i < NPER * CAP / 2; i += NT) {
        int2 v = ld_i2(bucket + (size_t)base * CAP + 2 * i);
        sbk[0][2 * i] = v.x; sbk[0][2 * i + 1] = v.y;
      }
      const float4* Wsv = reinterpret_cast<const float4*>(Wself + (l + 1) * 4096);
      const float4* Wnv = reinterpret_cast<const float4*>(Wneigh + (l + 1) * 4096);
      for (int i = tid; i < 1024; i += NT) {
        reinterpret_cast<float4*>(sWs)[i] = Wsv[i];
        reinterpret_cast<float4*>(sWn)[i] = Wnv[i];
      }
      grid_barrier(arr, flag, l + 2);   // prev layer's h now LLC-visible
    }
  }

  // ---- epilogue: restage MLP weights (warm L2), s-MLP, reduce, out ---------
  if (tid < 512)
    reinterpret_cast<float4*>(sWs)[tid] = reinterpret_cast<const float4*>(W1)[tid];
  if (tid < 256)
    reinterpret_cast<float4*>(sWs + 2048)[tid] = reinterpret_cast<const float4*>(W2)[tid];
  if (tid < 32) { sWn[tid] = W3[tid]; sWn[32 + tid] = b1[tid]; sWn[64 + tid] = b2[tid]; }
  if (tid == 0) sWn[96] = b3[0];
  __syncthreads();

  if (tid < 64) {      // wave 0: 55 node-MLPs + Wp-weighted reduce
    float v = 0.f;
    if (tid < NPER) {
      float x[64];
#pragma unroll
      for (int i = 0; i < 64; i++) x[i] = sh[tid][i];
      float rr = mlp_lds(x, sWs, sWs + 2048, sWn, sWn + 32, sWn + 64, sWn[96]);
      v = rr * sWp[tid];
    }
#pragma unroll
    for (int off = 32; off > 0; off >>= 1) v += __shfl_down(v, off, 64);
    if (tid == 0) sgsum = v;
  }
  __syncthreads();

  if (tid < KK) {
    const int* id = ids + ((size_t)b * KK + tid) * 3;
    int i0 = id[0], i1 = id[1], i2 = id[2];
    float o = sgsum + sbp_s;
    o = fmaf(t_l[i0], sWp[NPER + 0], o);
    o = fmaf(t_l[i1], sWp[NPER + 1], o);
    o = fmaf(t_l[i2], sWp[NPER + 2], o);
    out[(size_t)b * KK + tid] = o;       // own-block only; kernel-end release
  }
}

// ---------------------------------------------------------------------------
extern "C" void kernel_launch(void* const* d_in, const int* in_sizes, int n_in,
                              void* d_out, int out_size, void* d_ws, size_t ws_size,
                              hipStream_t stream) {
  const float* coords = (const float*)d_in[0];
  const int*   src    = (const int*)d_in[1];
  const int*   dst    = (const int*)d_in[2];
  const int*   ids    = (const int*)d_in[3];
  const float* We     = (const float*)d_in[4];
  const float* be     = (const float*)d_in[5];
  const float* Wself  = (const float*)d_in[6];
  const float* Wneigh = (const float*)d_in[7];
  const float* gb     = (const float*)d_in[8];
  const float* W1     = (const float*)d_in[9];
  const float* b1     = (const float*)d_in[10];
  const float* W2     = (const float*)d_in[11];
  const float* b2     = (const float*)d_in[12];
  const float* W3     = (const float*)d_in[13];
  const float* b3     = (const float*)d_in[14];
  const float* Wp     = (const float*)d_in[15];
  const float* bp     = (const float*)d_in[16];
  float* out = (float*)d_out;

  float* ws = (float*)d_ws;
  float* h0 = ws;                          // NN*64 floats
  float* h1 = h0 + (size_t)NN * EMB;       // NN*64 floats
  int* deg    = (int*)(h1 + (size_t)NN * EMB);  // NN ints
  int* arr    = deg + NN;                  // NB arrival slots
  int* flag   = arr + NB;                  // release flag (+pad)
  int* bucket = flag + 16;                 // NN*CAP ints (8B-aligned)

  // 1. zero deg + arrival slots + flag (ws is 0xAA-poisoned every call)
  init_kernel<<<(ZERO_N + 255) / 256, 256, 0, stream>>>(deg);
  // 2. everything else in one resident kernel (3 internal grid barriers)
  mega_kernel<<<NB, NT, 0, stream>>>(
      coords, src, dst, ids, We, be, Wself, Wneigh, gb,
      W1, b1, W2, b2, W3, b3, Wp, bp,
      h0, h1, deg, bucket, arr, flag, out);
}

// Round 14
// 159.768 us; speedup vs baseline: 3.8235x; 1.0811x over previous
//
#include <hip/hip_runtime.h>
#include <hip/hip_bf16.h>

// Problem constants (fixed by the reference)
constexpr int NB   = 256;           // graphs == grid size of mega kernel
constexpr int KK   = 256;           // destroy sets per graph
constexpr int NPER = 55;            // nodes per graph
constexpr int NN   = NB * NPER;     // 14080 nodes
constexpr int EMB  = 64;
constexpr int CAP  = 32;            // bucket capacity (verified safe)
constexpr int NT   = 512;           // threads per block (8 waves/CU)

// ---------------------------------------------------------------------------
// LLC-coherent (agent-scope, relaxed) scalar ops for CROSS-BLOCK data only.
// Stores bypass L1/L2 -> no barrier cache maintenance needed. Readers use
// PLAIN cached loads, valid because every h buffer is written exactly once
// and never plain-read before its producing barrier (write-once discipline).
using ull = unsigned long long;
__device__ __forceinline__ void st_f1(float* p, float x) {
  union { float f; unsigned u; } v; v.f = x;
  __hip_atomic_store((unsigned*)p, v.u, __ATOMIC_RELAXED, __HIP_MEMORY_SCOPE_AGENT);
}
__device__ __forceinline__ void st_f2(float* p, float x, float y) {
  union { float f[2]; ull u; } v; v.f[0] = x; v.f[1] = y;
  __hip_atomic_store((ull*)p, v.u, __ATOMIC_RELAXED, __HIP_MEMORY_SCOPE_AGENT);
}
__device__ __forceinline__ void st_i1(int* p, int x) {
  __hip_atomic_store(p, x, __ATOMIC_RELAXED, __HIP_MEMORY_SCOPE_AGENT);
}
__device__ __forceinline__ int ld_i1(const int* p) {
  return __hip_atomic_load(p, __ATOMIC_RELAXED, __HIP_MEMORY_SCOPE_AGENT);
}

// ---------------------------------------------------------------------------
// init: zero deg[NN] + arr[NB] + flag (ws is 0xAA-poisoned before every call).
constexpr int ZERO_N = NN + NB + 16;
__global__ __launch_bounds__(256) void init_kernel(int* __restrict__ p) {
  int i = blockIdx.x * 256 + threadIdx.x;
  if (i < ZERO_N) p[i] = 0;
}

// ---------------------------------------------------------------------------
// Fence-free grid barrier (R13-proven). __syncthreads() drains vmcnt (sc
// stores acked at LLC) before arrival; signal_fence stops compiler hoisting
// of the subsequent plain loads (no cache ops emitted).
__device__ __forceinline__ void grid_barrier(int* arr, int* flag, int ep) {
  __syncthreads();                 // all waves' sc-stores drained (vmcnt)
  int tid = threadIdx.x;
  if (blockIdx.x == 0) {
    if (tid == 0) st_i1(&arr[0], ep);
    if (tid < NB) {
      while (ld_i1(&arr[tid]) < ep) __builtin_amdgcn_s_sleep(8);
    }
    __syncthreads();               // all 256 slots observed
    if (tid == 0) st_i1(flag, ep);
  } else {
    if (tid == 0) {
      st_i1(&arr[blockIdx.x], ep);
      while (ld_i1(flag) < ep) __builtin_amdgcn_s_sleep(8);
    }
  }
  __atomic_signal_fence(__ATOMIC_SEQ_CST);   // compiler-only ordering
  __syncthreads();
}

// ---------------------------------------------------------------------------
// All-thread parallel MLP over the block's 55 rows in sh:
// 16 nodes/pass x 32 lanes (one hidden unit each); LDS scratch hands layer-1
// activations to layer-2; 32-lane shuffle reduce for the final dot.
// res[node] = MLP(sh[node]). scr needs 16*32 floats.
__device__ __forceinline__ void mlp_all(const float (&sh)[NPER][EMB],
    float* scr, const float* sW1, const float* sW2, const float* sW3,
    const float* sb1, const float* sb2, float b3v, float* res, int tid) {
  int grp = tid >> 5;        // 0..15
  int u   = tid & 31;
#pragma unroll
  for (int pass = 0; pass < 4; pass++) {
    int node = pass * 16 + grp;
    if (node < NPER) {
      float a = sb1[u];
#pragma unroll
      for (int i = 0; i < 64; i++) a = fmaf(sh[node][i], sW1[i * 32 + u], a);
      a = (a >= 0.f) ? a : 0.01f * a;
      scr[grp * 32 + u] = a;
    }
    __syncthreads();
    if (node < NPER) {
      float c = sb2[u];
#pragma unroll
      for (int i = 0; i < 32; i++) c = fmaf(scr[grp * 32 + i], sW2[i * 32 + u], c);
      c = (c >= 0.f) ? c : 0.01f * c;
      float v = c * sW3[u];
#pragma unroll
      for (int off = 16; off > 0; off >>= 1) v += __shfl_xor(v, off, 32);
      if (u == 0) res[node] = v + b3v;
    }
    __syncthreads();
  }
}

// ---------------------------------------------------------------------------
__global__ __launch_bounds__(NT) void mega_kernel(
    const float* __restrict__ coords, const int* __restrict__ src,
    const int* __restrict__ dst, const int* __restrict__ ids,
    const float* __restrict__ We, const float* __restrict__ be,
    const float* __restrict__ Wself, const float* __restrict__ Wneigh,
    const float* __restrict__ gnnb,
    const float* __restrict__ W1, const float* __restrict__ b1,
    const float* __restrict__ W2, const float* __restrict__ b2,
    const float* __restrict__ W3, const float* __restrict__ b3,
    const float* __restrict__ Wp, const float* __restrict__ bp,
    float* __restrict__ h0, float* __restrict__ h1, float* __restrict__ h2,
    int* __restrict__ deg, int* __restrict__ bucket,
    int* __restrict__ arr, int* __restrict__ flag,
    float* __restrict__ out) {
  // LDS ~61.9 KB: 1 block/CU, 8 waves
  __shared__ __align__(16) float sWs[4096];       // layer Wself | MLP W1,W2
  __shared__ __align__(16) float sWn[4096];       // layer Wneigh | MLP W3/b1/b2/b3
  __shared__ __align__(16) float sh[NPER][EMB];   // own h rows (current layer)
  __shared__ __align__(16) float uni[NPER * EMB]; // sa | sbk | MLP scratch
  __shared__ int   sdeg[NPER];
  __shared__ float t_l[NPER];
  __shared__ float s_arr[NPER];
  __shared__ float sWp[NPER + 3];
  __shared__ float sgsum, sbp_s;

  float (*sa)[EMB]  = reinterpret_cast<float (*)[EMB]>(uni);
  int   (*sbk)[CAP] = reinterpret_cast<int (*)[CAP]>(uni);

  int tid = threadIdx.x;
  int b = blockIdx.x;
  int base = b * NPER;

  // ---- prologue: MLP weights + constants + edge fill -----------------------
  if (tid < NPER + 3) sWp[tid] = Wp[tid];
  if (tid == 0) sbp_s = bp[0];
  if (tid < 512)
    reinterpret_cast<float4*>(sWs)[tid] = reinterpret_cast<const float4*>(W1)[tid];
  if (tid < 256)
    reinterpret_cast<float4*>(sWs + 2048)[tid] = reinterpret_cast<const float4*>(W2)[tid];
  if (tid < 32) { sWn[tid] = W3[tid]; sWn[32 + tid] = b1[tid]; sWn[64 + tid] = b2[tid]; }
  if (tid == 0) sWn[96] = b3[0];
  if (tid < 8 * NPER) {                    // 440 edges of this graph's slice
    int e = b * (8 * NPER) + tid;
    int d = dst[e];
    int s = src[e];
    int pos = atomicAdd(&deg[d], 1);       // device RMW at LLC
    if (pos < CAP) st_i1(&bucket[d * CAP + pos], s);   // sc (cross-block)
  }

  // ---- embed own 55 nodes -> sh + h0 (sc stores) ---------------------------
  if (tid < NPER) {
    int n = base + tid;
    float cx = coords[n * 2], cy = coords[n * 2 + 1];
    float x[64];
#pragma unroll
    for (int i = 0; i < 64; i++)
      x[i] = fmaf(cx, We[i], fmaf(cy, We[64 + i], be[i]));
    float* hv = h0 + (size_t)n * 64;
#pragma unroll
    for (int i = 0; i < 32; i++) st_f2(hv + 2 * i, x[2 * i], x[2 * i + 1]);
#pragma unroll
    for (int i = 0; i < 64; i++) sh[tid][i] = x[i];
  }
  __syncthreads();   // sh + MLP weights visible to all waves

  // ---- t-MLP on embeddings, all 512 threads (uni = scratch) ----------------
  mlp_all(sh, uni, sWs, sWs + 2048, sWn, sWn + 32, sWn + 64, sWn[96], t_l, tid);

  // stage layer-0 weights BEFORE barrier (immutable; overlaps arrival skew)
  {
    const float4* Wsv = reinterpret_cast<const float4*>(Wself);
    const float4* Wnv = reinterpret_cast<const float4*>(Wneigh);
    for (int i = tid; i < 1024; i += NT) {
      reinterpret_cast<float4*>(sWs)[i] = Wsv[i];
      reinterpret_cast<float4*>(sWn)[i] = Wnv[i];
    }
  }

  grid_barrier(arr, flag, 1);        // h0 + buckets LLC-visible
  if (tid < NPER) sdeg[tid] = min(deg[base + tid], CAP);   // plain (fresh)

  // ---- 3 GNN layers; write-once: h0 -> h1 -> h2 -> (LDS only) --------------
  for (int l = 0; l < 3; l++) {
    const float* hin  = (l == 0) ? h0 : (l == 1) ? h1 : h2;
    float*       hout = (l == 0) ? h1 : h2;     // unused for l==2
    const float* gbl = gnnb + l * 64;

    // stage this block's buckets into LDS (plain int4; warm L2 after l0)
    if (l == 0) {
      for (int i = tid; i < NPER * CAP / 4; i += NT)
        reinterpret_cast<int4*>(uni)[i] =
            reinterpret_cast<const int4*>(bucket + (size_t)base * CAP)[i];
      __syncthreads();
    }

    // ---- gather: 8 lanes/node, 8 dims each; plain float4 (L1/L2 cached) ----
    int r = tid >> 3, o = tid & 7;
    float a0 = 0.f, a1 = 0.f, a2 = 0.f, a3 = 0.f;
    float a4 = 0.f, a5 = 0.f, a6 = 0.f, a7 = 0.f;
    if (r < NPER) {
      int dg = sdeg[r];
      size_t oo = (size_t)o * 8;
      for (int e0 = 0; e0 < dg; e0 += 2) {
        bool ok1 = (e0 + 1 < dg);
        int s0 = sbk[r][e0];
        int s1 = ok1 ? sbk[r][e0 + 1] : s0;
        const float4* p0 = reinterpret_cast<const float4*>(hin + (size_t)s0 * 64 + oo);
        const float4* p1 = reinterpret_cast<const float4*>(hin + (size_t)s1 * 64 + oo);
        float4 u0 = p0[0], u1 = p0[1];
        float4 w0 = p1[0], w1 = p1[1];
        a0 += u0.x; a1 += u0.y; a2 += u0.z; a3 += u0.w;
        a4 += u1.x; a5 += u1.y; a6 += u1.z; a7 += u1.w;
        if (ok1) {
          a0 += w0.x; a1 += w0.y; a2 += w0.z; a3 += w0.w;
          a4 += w1.x; a5 += w1.y; a6 += w1.z; a7 += w1.w;
        }
      }
    }
    __syncthreads();   // all sbk reads done (sa overwrites the same LDS)
    if (r < NPER) {
      float4* sap = reinterpret_cast<float4*>(&sa[r][o * 8]);
      sap[0] = make_float4(a0, a1, a2, a3);
      sap[1] = make_float4(a4, a5, a6, a7);
    }
    __syncthreads();   // sa ready

    // ---- dense: chunk-hoisted weights in regs, broadcast b128 sh/sa ----
    int j = tid & 63;
    int g = tid >> 6;                       // 0..7
    int nrows = (g < 7) ? 7 : 6;            // 7*7+6 = 55
    int rbase = g * 7;
    float bj = gbl[j];
    float acc[7];
#pragma unroll
    for (int nn = 0; nn < 7; nn++) acc[nn] = bj;
#pragma unroll
    for (int c = 0; c < 16; c++) {
      int ib = c * 4;
      float w0 = sWs[(ib + 0) * 64 + j], w1 = sWs[(ib + 1) * 64 + j];
      float w2 = sWs[(ib + 2) * 64 + j], w3 = sWs[(ib + 3) * 64 + j];
      float v0 = sWn[(ib + 0) * 64 + j], v1 = sWn[(ib + 1) * 64 + j];
      float v2 = sWn[(ib + 2) * 64 + j], v3 = sWn[(ib + 3) * 64 + j];
#pragma unroll
      for (int nn = 0; nn < 7; nn++) {
        if (nn < nrows) {
          int rr = rbase + nn;
          float4 hs = *reinterpret_cast<const float4*>(&sh[rr][ib]);
          float4 as = *reinterpret_cast<const float4*>(&sa[rr][ib]);
          float t = acc[nn];
          t = fmaf(hs.x, w0, t); t = fmaf(hs.y, w1, t);
          t = fmaf(hs.z, w2, t); t = fmaf(hs.w, w3, t);
          t = fmaf(as.x, v0, t); t = fmaf(as.y, v1, t);
          t = fmaf(as.z, v2, t); t = fmaf(as.w, v3, t);
          acc[nn] = t;
        }
      }
    }
    float res[7];
#pragma unroll
    for (int nn = 0; nn < 7; nn++) {
      if (nn < nrows) {
        int rr = rbase + nn;
        res[nn] = ((acc[nn] > 0.f) ? acc[nn] : 0.f) + sh[rr][j];
        if (l != 2) st_f1(&hout[(size_t)(base + rr) * 64 + j], res[nn]);  // sc
      }
    }
    __syncthreads();   // all sh reads done
#pragma unroll
    for (int nn = 0; nn < 7; nn++)
      if (nn < nrows) sh[rbase + nn][j] = res[nn];
    __syncthreads();   // sh = next layer's input (or final h)

    // ---- pre-barrier staging for next layer (all warm L2 now) ----
    if (l < 2) {
      for (int i = tid; i < NPER * CAP / 4; i += NT)
        reinterpret_cast<int4*>(uni)[i] =
            reinterpret_cast<const int4*>(bucket + (size_t)base * CAP)[i];
      const float4* Wsv = reinterpret_cast<const float4*>(Wself + (l + 1) * 4096);
      const float4* Wnv = reinterpret_cast<const float4*>(Wneigh + (l + 1) * 4096);
      for (int i = tid; i < 1024; i += NT) {
        reinterpret_cast<float4*>(sWs)[i] = Wsv[i];
        reinterpret_cast<float4*>(sWn)[i] = Wnv[i];
      }
      grid_barrier(arr, flag, l + 2);   // prev layer's h now LLC-visible
    }
  }

  // ---- epilogue: restage MLP weights (warm L2), parallel s-MLP, reduce, out
  if (tid < 512)
    reinterpret_cast<float4*>(sWs)[tid] = reinterpret_cast<const float4*>(W1)[tid];
  if (tid < 256)
    reinterpret_cast<float4*>(sWs + 2048)[tid] = reinterpret_cast<const float4*>(W2)[tid];
  if (tid < 32) { sWn[tid] = W3[tid]; sWn[32 + tid] = b1[tid]; sWn[64 + tid] = b2[tid]; }
  if (tid == 0) sWn[96] = b3[0];
  __syncthreads();

  mlp_all(sh, uni, sWs, sWs + 2048, sWn, sWn + 32, sWn + 64, sWn[96], s_arr, tid);

  if (tid < 64) {      // Wp-weighted reduce over 55 node scores
    float v = (tid < NPER) ? s_arr[tid] * sWp[tid] : 0.f;
#pragma unroll
    for (int off = 32; off > 0; off >>= 1) v += __shfl_down(v, off, 64);
    if (tid == 0) sgsum = v;
  }
  __syncthreads();

  if (tid < KK) {
    const int* id = ids + ((size_t)b * KK + tid) * 3;
    int i0 = id[0], i1 = id[1], i2 = id[2];
    float o = sgsum + sbp_s;
    o = fmaf(t_l[i0], sWp[NPER + 0], o);
    o = fmaf(t_l[i1], sWp[NPER + 1], o);
    o = fmaf(t_l[i2], sWp[NPER + 2], o);
    out[(size_t)b * KK + tid] = o;       // own-block; kernel-end release
  }
}

// ---------------------------------------------------------------------------
extern "C" void kernel_launch(void* const* d_in, const int* in_sizes, int n_in,
                              void* d_out, int out_size, void* d_ws, size_t ws_size,
                              hipStream_t stream) {
  const float* coords = (const float*)d_in[0];
  const int*   src    = (const int*)d_in[1];
  const int*   dst    = (const int*)d_in[2];
  const int*   ids    = (const int*)d_in[3];
  const float* We     = (const float*)d_in[4];
  const float* be     = (const float*)d_in[5];
  const float* Wself  = (const float*)d_in[6];
  const float* Wneigh = (const float*)d_in[7];
  const float* gb     = (const float*)d_in[8];
  const float* W1     = (const float*)d_in[9];
  const float* b1     = (const float*)d_in[10];
  const float* W2     = (const float*)d_in[11];
  const float* b2     = (const float*)d_in[12];
  const float* W3     = (const float*)d_in[13];
  const float* b3     = (const float*)d_in[14];
  const float* Wp     = (const float*)d_in[15];
  const float* bp     = (const float*)d_in[16];
  float* out = (float*)d_out;

  float* ws = (float*)d_ws;
  float* h0 = ws;                          // NN*64 floats (write-once)
  float* h1 = h0 + (size_t)NN * EMB;       // NN*64 floats (write-once)
  float* h2 = h1 + (size_t)NN * EMB;       // NN*64 floats (write-once)
  int* deg    = (int*)(h2 + (size_t)NN * EMB);  // NN ints
  int* arr    = deg + NN;                  // NB arrival slots
  int* flag   = arr + NB;                  // release flag (+pad to 16B)
  int* bucket = flag + 16;                 // NN*CAP ints (16B-aligned)

  // 1. zero deg + arrival slots + flag (ws is 0xAA-poisoned every call)
  init_kernel<<<(ZERO_N + 255) / 256, 256, 0, stream>>>(deg);
  // 2. everything else in one resident kernel (3 internal grid barriers)
  mega_kernel<<<NB, NT, 0, stream>>>(
      coords, src, dst, ids, We, be, Wself, Wneigh, gb,
      W1, b1, W2, b2, W3, b3, Wp, bp,
      h0, h1, h2, deg, bucket, arr, flag, out);
}